// Round 6
// baseline (421.136 us; speedup 1.0000x reference)
//
#include <hip/hip_runtime.h>

#define N_NODES 50000
#define N_EDGES 800000
#define D 64          // D_IN == D_OUT
#define ED 32         // EDGE_DIM
#define BN_EPS 1e-5f

// ---- workspace layout (32-bit word indices) -------------------------------
#define WS_SUMS     0
#define WS_SUMSQ    64
#define WS_PART     128                       // 64 ints: scan partials
#define WS_DEG      256
#define WS_ZERO_END (WS_DEG + N_NODES)        // memset [0, here) ~201 KB
#define WS_OFF      WS_ZERO_END               // 50256
#define WS_CURSOR   (WS_OFF + N_NODES + 4)    // 100260
#define WS_SRC2     (WS_CURSOR + N_NODES)     // 150260 (byte 601040, 8B ok)
#define WS_AGGEA    (WS_SRC2 + 2 * N_EDGES)   // 1750260 (byte 7001040, 16B ok)
#define WS_PRE      (WS_AGGEA + N_NODES * ED) // 3350260 (byte 13401040, 16B ok)
#define WS_H        (WS_PRE + N_NODES * D)    // 6550260 (byte 26201040, 16B ok)
// total = WS_H + N_NODES*D = 9750260 words ~ 39 MB (ws proved >= 68 MB)

#define SCAN_BLOCKS 50   // 50 x 1000 = N_NODES exactly
#define N_GRP ((N_NODES + 63) / 64)   // 782 wave-tasks for lane=node kernels

// ---------------------------------------------------------------------------
// degree histogram (int atomics, ~800k ops)
__global__ __launch_bounds__(256) void count_kernel(
    const int* __restrict__ dst, int* __restrict__ deg)
{
    int i = blockIdx.x * 256 + threadIdx.x;
    const int stride = gridDim.x * 256;
    for (; i < N_EDGES / 4; i += stride) {
        int4 d = ((const int4*)dst)[i];
        atomicAdd(&deg[d.x], 1);
        atomicAdd(&deg[d.y], 1);
        atomicAdd(&deg[d.z], 1);
        atomicAdd(&deg[d.w], 1);
    }
}

// per-block partial sums over 1000 ints (coalesced int4)
__global__ __launch_bounds__(256) void scan_partial_kernel(
    const int* __restrict__ deg, int* __restrict__ partial)
{
    __shared__ int sR[256];
    const int t = threadIdx.x;
    const int base = blockIdx.x * 1000;
    int local = 0;
    if (t < 250) {
        int4 d = ((const int4*)(deg + base))[t];
        local = d.x + d.y + d.z + d.w;
    }
    sR[t] = local;
    __syncthreads();
    for (int o = 128; o > 0; o >>= 1) {
        if (t < o) sR[t] += sR[t + o];
        __syncthreads();
    }
    if (t == 0) partial[blockIdx.x] = sR[0];
}

// block-local scan + in-kernel top scan of the 50 partials; writes off & cursor
__global__ __launch_bounds__(256) void scan_write_kernel(
    const int* __restrict__ deg, const int* __restrict__ partial,
    int* __restrict__ off, int* __restrict__ cursor)
{
    __shared__ int sS[256];
    __shared__ int sTop;
    const int t = threadIdx.x;
    if (t < 64) {                       // wave 0: exclusive scan of partials
        int v = (t < SCAN_BLOCKS) ? partial[t] : 0;
        int inc = v;
        for (int o = 1; o < 64; o <<= 1) {
            int u = __shfl_up(inc, o);
            if (t >= o) inc += u;
        }
        if (t == blockIdx.x) sTop = inc - v;
    }
    const int base = blockIdx.x * 1000;
    int4 d = make_int4(0, 0, 0, 0);
    int local = 0;
    if (t < 250) {
        d = ((const int4*)(deg + base))[t];
        local = d.x + d.y + d.z + d.w;
    }
    sS[t] = local;
    __syncthreads();
    for (int o = 1; o < 256; o <<= 1) {
        int v = sS[t];
        int add = (t >= o) ? sS[t - o] : 0;
        __syncthreads();
        sS[t] = v + add;
        __syncthreads();
    }
    if (t < 250) {
        int p = sTop + sS[t] - local;   // exclusive prefix
        int4 o4 = make_int4(p, p + d.x, p + d.x + d.y, p + d.x + d.y + d.z);
        ((int4*)(off + base))[t] = o4;
        ((int4*)(cursor + base))[t] = o4;
    }
    if (blockIdx.x == 0 && t == 0) off[N_NODES] = N_EDGES;
}

// dst-sorted (eid, src) pairs (6.4 MB random 8B writes)
__global__ __launch_bounds__(256) void scatter_kernel(
    const int* __restrict__ ei, int* __restrict__ cursor, int2* __restrict__ sorted)
{
    int i = blockIdx.x * 256 + threadIdx.x;
    const int stride = gridDim.x * 256;
    for (; i < N_EDGES; i += stride) {
        const int src = ei[i];
        const int d = ei[N_EDGES + i];
        const int pos = atomicAdd(&cursor[d], 1);
        sorted[pos] = make_int2(i, src);
    }
}

// ---------------------------------------------------------------------------
// Pure gather, no LDS -> full occupancy. Per node (wave):
//   pre[node]   = x[node] + sum_e x[src[e]]        (256B rows, lanes 0..63)
//   aggEA[node] = sum_e ea[eid[e]]                 (128B rows, 2 edges/instr)
__global__ __launch_bounds__(256) void agg_kernel(
    const float* __restrict__ x, const float* __restrict__ ea,
    const int* __restrict__ off, const int2* __restrict__ sorted,
    float* __restrict__ pre, float* __restrict__ aggEA)
{
    const int f = threadIdx.x & 63;
    const int w = threadIdx.x >> 6;
    const int fe = f & 31;
    const bool lo = (f < 32);
    const int nwv = gridDim.x * 4;
    for (int node = blockIdx.x * 4 + w; node < N_NODES; node += nwv) {
        const int start = __builtin_amdgcn_readfirstlane(off[node]);
        const int n     = __builtin_amdgcn_readfirstlane(off[node + 1]) - start;
        const int2* sp = sorted + start;
        float s = x[(size_t)node * D + f];
        float ax = 0.f, ay = 0.f;
        int it = 0;
        if (n >= 8) {
            int2 c0 = sp[0], c1 = sp[1], c2 = sp[2], c3 = sp[3];
            int2 c4 = sp[4], c5 = sp[5], c6 = sp[6], c7 = sp[7];
            for (; it + 16 <= n; it += 8) {
                const int2 n0 = sp[it + 8],  n1 = sp[it + 9];
                const int2 n2 = sp[it + 10], n3 = sp[it + 11];
                const int2 n4 = sp[it + 12], n5 = sp[it + 13];
                const int2 n6 = sp[it + 14], n7 = sp[it + 15];
                s += x[(size_t)c0.y * D + f]; s += x[(size_t)c1.y * D + f];
                s += x[(size_t)c2.y * D + f]; s += x[(size_t)c3.y * D + f];
                s += x[(size_t)c4.y * D + f]; s += x[(size_t)c5.y * D + f];
                s += x[(size_t)c6.y * D + f]; s += x[(size_t)c7.y * D + f];
                ax += ea[(size_t)(lo ? c0.x : c1.x) * ED + fe];
                ax += ea[(size_t)(lo ? c2.x : c3.x) * ED + fe];
                ay += ea[(size_t)(lo ? c4.x : c5.x) * ED + fe];
                ay += ea[(size_t)(lo ? c6.x : c7.x) * ED + fe];
                c0 = n0; c1 = n1; c2 = n2; c3 = n3;
                c4 = n4; c5 = n5; c6 = n6; c7 = n7;
            }
            s += x[(size_t)c0.y * D + f]; s += x[(size_t)c1.y * D + f];
            s += x[(size_t)c2.y * D + f]; s += x[(size_t)c3.y * D + f];
            s += x[(size_t)c4.y * D + f]; s += x[(size_t)c5.y * D + f];
            s += x[(size_t)c6.y * D + f]; s += x[(size_t)c7.y * D + f];
            ax += ea[(size_t)(lo ? c0.x : c1.x) * ED + fe];
            ax += ea[(size_t)(lo ? c2.x : c3.x) * ED + fe];
            ay += ea[(size_t)(lo ? c4.x : c5.x) * ED + fe];
            ay += ea[(size_t)(lo ? c6.x : c7.x) * ED + fe];
            it += 8;
        }
        for (; it < n; ++it) {               // tail: 0..7 edges
            const int2 p = sp[it];
            s += x[(size_t)p.y * D + f];
            if (lo) ax += ea[(size_t)p.x * ED + fe];
        }
        pre[(size_t)node * D + f] = s;
        ax += ay;
        ax += __shfl_xor(ax, 32);            // even-edge + odd-edge halves
        if (lo) aggEA[(size_t)node * ED + fe] = ax;
    }
}

// ---------------------------------------------------------------------------
// MLP1, lane=node, CHUNKED (anti-spill): phase 1 builds val[64] in regs
// (live: 64+32), phase 2 emits 16 outputs at a time (live: 64+16).
__global__ __launch_bounds__(256) void mlp1_kernel(
    const float* __restrict__ pre, const float* __restrict__ aggEA,
    const int* __restrict__ deg,
    const float* __restrict__ We, const float* __restrict__ be,
    const float* __restrict__ W1, const float* __restrict__ b1,
    float* __restrict__ h)
{
    __shared__ float4 sWe[ED][16];   // We[j][4i..]  8 KB
    __shared__ float4 sW1[D][16];    // W1[k][4i..] 16 KB
    __shared__ float4 sbe[16];
    __shared__ float4 sb1[16];
    const int tid = threadIdx.x;
    for (int i = tid; i < ED * 16; i += 256) sWe[i >> 4][i & 15] = ((const float4*)We)[i];
    for (int i = tid; i < D * 16; i += 256)  sW1[i >> 4][i & 15] = ((const float4*)W1)[i];
    if (tid < 16)       sbe[tid] = ((const float4*)be)[tid];
    else if (tid < 32)  sb1[tid - 16] = ((const float4*)b1)[tid - 16];
    __syncthreads();

    const int lane = tid & 63;
    const int w = tid >> 6;
    for (int grp = blockIdx.x * 4 + w; grp < N_GRP; grp += gridDim.x * 4) {
        const int node = grp * 64 + lane;
        if (node >= N_NODES) continue;
        float vv[D];
        #pragma unroll
        for (int i = 0; i < 16; ++i)
            ((float4*)vv)[i] = ((const float4*)(pre + (size_t)node * D))[i];
        {
            float av[ED];
            #pragma unroll
            for (int i = 0; i < 8; ++i)
                ((float4*)av)[i] = ((const float4*)(aggEA + (size_t)node * ED))[i];
            const float dg = (float)deg[node];
            #pragma unroll
            for (int i = 0; i < 16; ++i) {
                const float4 b = sbe[i];
                vv[4*i+0] += dg * b.x; vv[4*i+1] += dg * b.y;
                vv[4*i+2] += dg * b.z; vv[4*i+3] += dg * b.w;
            }
            #pragma unroll
            for (int j = 0; j < ED; ++j) {
                const float aj = av[j];
                #pragma unroll
                for (int i = 0; i < 16; ++i) {
                    const float4 wv = sWe[j][i];
                    vv[4*i+0] += aj * wv.x; vv[4*i+1] += aj * wv.y;
                    vv[4*i+2] += aj * wv.z; vv[4*i+3] += aj * wv.w;
                }
            }
        }
        float* hp = h + (size_t)node * D;
        #pragma unroll
        for (int c = 0; c < 4; ++c) {        // 16 output features per chunk
            float4 o0 = sb1[4*c+0], o1 = sb1[4*c+1];
            float4 o2 = sb1[4*c+2], o3 = sb1[4*c+3];
            #pragma unroll
            for (int k = 0; k < D; ++k) {
                const float vk = vv[k];
                const float4 w0 = sW1[k][4*c+0];
                const float4 w1 = sW1[k][4*c+1];
                const float4 w2 = sW1[k][4*c+2];
                const float4 w3 = sW1[k][4*c+3];
                o0.x += vk*w0.x; o0.y += vk*w0.y; o0.z += vk*w0.z; o0.w += vk*w0.w;
                o1.x += vk*w1.x; o1.y += vk*w1.y; o1.z += vk*w1.z; o1.w += vk*w1.w;
                o2.x += vk*w2.x; o2.y += vk*w2.y; o2.z += vk*w2.z; o2.w += vk*w2.w;
                o3.x += vk*w3.x; o3.y += vk*w3.y; o3.z += vk*w3.z; o3.w += vk*w3.w;
            }
            ((float4*)hp)[4*c+0] = o0; ((float4*)hp)[4*c+1] = o1;
            ((float4*)hp)[4*c+2] = o2; ((float4*)hp)[4*c+3] = o3;
        }
    }
}

// ---------------------------------------------------------------------------
// BN stats: coalesced streaming pass over h (lane=feature), per-block reduce.
__global__ __launch_bounds__(256) void bn_stats_kernel(
    const float* __restrict__ h, float* __restrict__ sums, float* __restrict__ sumsq)
{
    __shared__ float sRed[2][4][D];
    const int f = threadIdx.x & 63;
    const int w = threadIdx.x >> 6;
    float ps = 0.f, pq = 0.f;
    const int nwv = gridDim.x * 4;
    for (int node = blockIdx.x * 4 + w; node < N_NODES; node += nwv) {
        const float v = h[(size_t)node * D + f];
        ps += v;
        pq += v * v;
    }
    sRed[0][w][f] = ps;
    sRed[1][w][f] = pq;
    __syncthreads();
    if (w == 0) {
        const float s = sRed[0][0][f] + sRed[0][1][f] + sRed[0][2][f] + sRed[0][3][f];
        const float q = sRed[1][0][f] + sRed[1][1][f] + sRed[1][2][f] + sRed[1][3][f];
        unsafeAtomicAdd(&sums[f], s);
        unsafeAtomicAdd(&sumsq[f], q);
    }
}

// ---------------------------------------------------------------------------
// MLP2, lane=node, CHUNKED: out = relu(h*sc+sh) @ W2 + b2
__global__ __launch_bounds__(256) void mlp2_kernel(
    const float* __restrict__ h, const float* __restrict__ W2,
    const float* __restrict__ b2, const float* __restrict__ sums,
    const float* __restrict__ sumsq, const float* __restrict__ gamma,
    const float* __restrict__ beta, float* __restrict__ out)
{
    __shared__ float4 sW2[D][16];    // 16 KB
    __shared__ float4 sb2[16];
    __shared__ float ssc[D];
    __shared__ float ssh[D];
    const int tid = threadIdx.x;
    for (int i = tid; i < D * 16; i += 256) sW2[i >> 4][i & 15] = ((const float4*)W2)[i];
    if (tid < 16) sb2[tid] = ((const float4*)b2)[tid];
    if (tid < 64) {
        const float inv_n = 1.0f / (float)N_NODES;
        const float mean = sums[tid] * inv_n;
        const float var  = sumsq[tid] * inv_n - mean * mean;   // biased, like jnp.var
        const float sc   = gamma[tid] * rsqrtf(var + BN_EPS);
        ssc[tid] = sc;
        ssh[tid] = beta[tid] - mean * sc;
    }
    __syncthreads();

    const int lane = tid & 63;
    const int w = tid >> 6;
    for (int grp = blockIdx.x * 4 + w; grp < N_GRP; grp += gridDim.x * 4) {
        const int node = grp * 64 + lane;
        if (node >= N_NODES) continue;
        float vv[D];
        #pragma unroll
        for (int i = 0; i < 16; ++i)
            ((float4*)vv)[i] = ((const float4*)(h + (size_t)node * D))[i];
        #pragma unroll
        for (int i = 0; i < 16; ++i) {
            const float4 c = ((const float4*)ssc)[i];
            const float4 s = ((const float4*)ssh)[i];
            float t;
            t = vv[4*i+0] * c.x + s.x; vv[4*i+0] = t > 0.f ? t : 0.f;
            t = vv[4*i+1] * c.y + s.y; vv[4*i+1] = t > 0.f ? t : 0.f;
            t = vv[4*i+2] * c.z + s.z; vv[4*i+2] = t > 0.f ? t : 0.f;
            t = vv[4*i+3] * c.w + s.w; vv[4*i+3] = t > 0.f ? t : 0.f;
        }
        float* op = out + (size_t)node * D;
        #pragma unroll
        for (int c = 0; c < 4; ++c) {
            float4 o0 = sb2[4*c+0], o1 = sb2[4*c+1];
            float4 o2 = sb2[4*c+2], o3 = sb2[4*c+3];
            #pragma unroll
            for (int k = 0; k < D; ++k) {
                const float vk = vv[k];
                const float4 w0 = sW2[k][4*c+0];
                const float4 w1 = sW2[k][4*c+1];
                const float4 w2 = sW2[k][4*c+2];
                const float4 w3 = sW2[k][4*c+3];
                o0.x += vk*w0.x; o0.y += vk*w0.y; o0.z += vk*w0.z; o0.w += vk*w0.w;
                o1.x += vk*w1.x; o1.y += vk*w1.y; o1.z += vk*w1.z; o1.w += vk*w1.w;
                o2.x += vk*w2.x; o2.y += vk*w2.y; o2.z += vk*w2.z; o2.w += vk*w2.w;
                o3.x += vk*w3.x; o3.y += vk*w3.y; o3.z += vk*w3.z; o3.w += vk*w3.w;
            }
            ((float4*)op)[4*c+0] = o0; ((float4*)op)[4*c+1] = o1;
            ((float4*)op)[4*c+2] = o2; ((float4*)op)[4*c+3] = o3;
        }
    }
}

// ---------------------------------------------------------------------------
extern "C" void kernel_launch(void* const* d_in, const int* in_sizes, int n_in,
                              void* d_out, int out_size, void* d_ws, size_t ws_size,
                              hipStream_t stream) {
    const float* x     = (const float*)d_in[0];
    const int*   ei    = (const int*)  d_in[1];   // [2, E] int32
    const float* ea    = (const float*)d_in[2];
    const float* We    = (const float*)d_in[3];
    const float* be    = (const float*)d_in[4];
    const float* W1    = (const float*)d_in[5];
    const float* b1    = (const float*)d_in[6];
    const float* gamma = (const float*)d_in[7];
    const float* beta  = (const float*)d_in[8];
    const float* W2    = (const float*)d_in[9];
    const float* b2    = (const float*)d_in[10];

    float* ws      = (float*)d_ws;
    float* sums    = ws + WS_SUMS;
    float* sumsq   = ws + WS_SUMSQ;
    int*   partial = (int*)(ws + WS_PART);
    int*   deg     = (int*)(ws + WS_DEG);
    int*   off     = (int*)(ws + WS_OFF);
    int*   cursor  = (int*)(ws + WS_CURSOR);
    int2*  sorted2 = (int2*)(ws + WS_SRC2);
    float* aggEA   = ws + WS_AGGEA;
    float* pre     = ws + WS_PRE;
    float* h       = ws + WS_H;

    hipMemsetAsync(ws, 0, (size_t)WS_ZERO_END * sizeof(float), stream);

    count_kernel       <<<784, 256, 0, stream>>>(ei + N_EDGES, deg);
    scan_partial_kernel<<<SCAN_BLOCKS, 256, 0, stream>>>(deg, partial);
    scan_write_kernel  <<<SCAN_BLOCKS, 256, 0, stream>>>(deg, partial, off, cursor);
    scatter_kernel     <<<1024, 256, 0, stream>>>(ei, cursor, sorted2);
    agg_kernel         <<<2048, 256, 0, stream>>>(x, ea, off, sorted2, pre, aggEA);
    mlp1_kernel        <<<196, 256, 0, stream>>>(pre, aggEA, deg, We, be, W1, b1, h);
    bn_stats_kernel    <<<512, 256, 0, stream>>>(h, sums, sumsq);
    mlp2_kernel        <<<196, 256, 0, stream>>>(h, W2, b2, sums, sumsq,
                                                 gamma, beta, (float*)d_out);
}

// Round 7
// 354.924 us; speedup vs baseline: 1.1866x; 1.1866x over previous
//
#include <hip/hip_runtime.h>

#define N_NODES 50000
#define N_EDGES 800000
#define D 64          // D_IN == D_OUT
#define ED 32         // EDGE_DIM
#define BN_EPS 1e-5f

// ---- workspace layout (32-bit word indices) -------------------------------
#define WS_SUMS     0
#define WS_SUMSQ    64
#define WS_PART     128                       // 64 ints: scan partials
#define WS_DEG      256
#define WS_ZERO_END (WS_DEG + N_NODES)        // memset [0, here) ~201 KB
#define WS_OFF      WS_ZERO_END               // 50256
#define WS_CURSOR   (WS_OFF + N_NODES + 4)    // 100260
#define WS_SRC2     (WS_CURSOR + N_NODES)     // 150260 (byte 601040, 8B ok)
#define WS_AGGEA    (WS_SRC2 + 2 * N_EDGES)   // 1750260 (byte 7001040, 16B ok)
#define WS_PRE      (WS_AGGEA + N_NODES * ED) // 3350260 (byte 13401040, 16B ok)
#define WS_H        (WS_PRE + N_NODES * D)    // 6550260 (byte 26201040, 16B ok)
#define WS_WC       (WS_H + N_NODES * D)      // 9750260 (byte 39001040, 16B ok)
#define WS_BEC      (WS_WC + ED * D)          // 9752308
// total = WS_BEC + 64 = 9752372 words ~ 39 MB (ws proved >= 68 MB)

#define SCAN_BLOCKS 50   // 50 x 1000 = N_NODES exactly
#define N_BLK ((N_NODES + 63) / 64)   // 782 GEMM tiles

// ---------------------------------------------------------------------------
// Fold edge MLP into main GEMM: wc = We@W1 [32x64], bec = be@W1 [64]
__global__ __launch_bounds__(256) void foldw_kernel(
    const float* __restrict__ We, const float* __restrict__ W1,
    const float* __restrict__ be, float* __restrict__ wc, float* __restrict__ bec)
{
    const int idx = blockIdx.x * 256 + threadIdx.x;
    if (idx < ED * D) {
        const int j = idx >> 6, f = idx & 63;
        float a = 0.f;
        for (int k = 0; k < D; ++k) a += We[j * D + k] * W1[k * D + f];
        wc[idx] = a;
    }
    if (idx < D) {
        float a = 0.f;
        for (int k = 0; k < D; ++k) a += be[k] * W1[k * D + idx];
        bec[idx] = a;
    }
}

// ---------------------------------------------------------------------------
// degree histogram (int atomics, ~800k ops)
__global__ __launch_bounds__(256) void count_kernel(
    const int* __restrict__ dst, int* __restrict__ deg)
{
    int i = blockIdx.x * 256 + threadIdx.x;
    const int stride = gridDim.x * 256;
    for (; i < N_EDGES / 4; i += stride) {
        int4 d = ((const int4*)dst)[i];
        atomicAdd(&deg[d.x], 1);
        atomicAdd(&deg[d.y], 1);
        atomicAdd(&deg[d.z], 1);
        atomicAdd(&deg[d.w], 1);
    }
}

// per-block partial sums over 1000 ints (coalesced int4)
__global__ __launch_bounds__(256) void scan_partial_kernel(
    const int* __restrict__ deg, int* __restrict__ partial)
{
    __shared__ int sR[256];
    const int t = threadIdx.x;
    const int base = blockIdx.x * 1000;
    int local = 0;
    if (t < 250) {
        int4 d = ((const int4*)(deg + base))[t];
        local = d.x + d.y + d.z + d.w;
    }
    sR[t] = local;
    __syncthreads();
    for (int o = 128; o > 0; o >>= 1) {
        if (t < o) sR[t] += sR[t + o];
        __syncthreads();
    }
    if (t == 0) partial[blockIdx.x] = sR[0];
}

// block-local scan + in-kernel top scan of the 50 partials; writes off & cursor
__global__ __launch_bounds__(256) void scan_write_kernel(
    const int* __restrict__ deg, const int* __restrict__ partial,
    int* __restrict__ off, int* __restrict__ cursor)
{
    __shared__ int sS[256];
    __shared__ int sTop;
    const int t = threadIdx.x;
    if (t < 64) {                       // wave 0: exclusive scan of partials
        int v = (t < SCAN_BLOCKS) ? partial[t] : 0;
        int inc = v;
        for (int o = 1; o < 64; o <<= 1) {
            int u = __shfl_up(inc, o);
            if (t >= o) inc += u;
        }
        if (t == blockIdx.x) sTop = inc - v;
    }
    const int base = blockIdx.x * 1000;
    int4 d = make_int4(0, 0, 0, 0);
    int local = 0;
    if (t < 250) {
        d = ((const int4*)(deg + base))[t];
        local = d.x + d.y + d.z + d.w;
    }
    sS[t] = local;
    __syncthreads();
    for (int o = 1; o < 256; o <<= 1) {
        int v = sS[t];
        int add = (t >= o) ? sS[t - o] : 0;
        __syncthreads();
        sS[t] = v + add;
        __syncthreads();
    }
    if (t < 250) {
        int p = sTop + sS[t] - local;   // exclusive prefix
        int4 o4 = make_int4(p, p + d.x, p + d.x + d.y, p + d.x + d.y + d.z);
        ((int4*)(off + base))[t] = o4;
        ((int4*)(cursor + base))[t] = o4;
    }
    if (blockIdx.x == 0 && t == 0) off[N_NODES] = N_EDGES;
}

// dst-sorted (eid, src) pairs (6.4 MB random 8B writes)
__global__ __launch_bounds__(256) void scatter_kernel(
    const int* __restrict__ ei, int* __restrict__ cursor, int2* __restrict__ sorted)
{
    int i = blockIdx.x * 256 + threadIdx.x;
    const int stride = gridDim.x * 256;
    for (; i < N_EDGES; i += stride) {
        const int src = ei[i];
        const int d = ei[N_EDGES + i];
        const int pos = atomicAdd(&cursor[d], 1);
        sorted[pos] = make_int2(i, src);
    }
}

// ---------------------------------------------------------------------------
// Pure gather, no LDS -> full occupancy. Per node (wave):
//   pre[node]   = x[node] + sum_e x[src[e]]        (256B rows, lanes 0..63)
//   aggEA[node] = sum_e ea[eid[e]]                 (128B rows, 2 edges/instr)
__global__ __launch_bounds__(256) void agg_kernel(
    const float* __restrict__ x, const float* __restrict__ ea,
    const int* __restrict__ off, const int2* __restrict__ sorted,
    float* __restrict__ pre, float* __restrict__ aggEA)
{
    const int f = threadIdx.x & 63;
    const int w = threadIdx.x >> 6;
    const int fe = f & 31;
    const bool lo = (f < 32);
    const int nwv = gridDim.x * 4;
    for (int node = blockIdx.x * 4 + w; node < N_NODES; node += nwv) {
        const int start = __builtin_amdgcn_readfirstlane(off[node]);
        const int n     = __builtin_amdgcn_readfirstlane(off[node + 1]) - start;
        const int2* sp = sorted + start;
        float s = x[(size_t)node * D + f];
        float ax = 0.f, ay = 0.f;
        int it = 0;
        if (n >= 8) {
            int2 c0 = sp[0], c1 = sp[1], c2 = sp[2], c3 = sp[3];
            int2 c4 = sp[4], c5 = sp[5], c6 = sp[6], c7 = sp[7];
            for (; it + 16 <= n; it += 8) {
                const int2 n0 = sp[it + 8],  n1 = sp[it + 9];
                const int2 n2 = sp[it + 10], n3 = sp[it + 11];
                const int2 n4 = sp[it + 12], n5 = sp[it + 13];
                const int2 n6 = sp[it + 14], n7 = sp[it + 15];
                s += x[(size_t)c0.y * D + f]; s += x[(size_t)c1.y * D + f];
                s += x[(size_t)c2.y * D + f]; s += x[(size_t)c3.y * D + f];
                s += x[(size_t)c4.y * D + f]; s += x[(size_t)c5.y * D + f];
                s += x[(size_t)c6.y * D + f]; s += x[(size_t)c7.y * D + f];
                ax += ea[(size_t)(lo ? c0.x : c1.x) * ED + fe];
                ax += ea[(size_t)(lo ? c2.x : c3.x) * ED + fe];
                ay += ea[(size_t)(lo ? c4.x : c5.x) * ED + fe];
                ay += ea[(size_t)(lo ? c6.x : c7.x) * ED + fe];
                c0 = n0; c1 = n1; c2 = n2; c3 = n3;
                c4 = n4; c5 = n5; c6 = n6; c7 = n7;
            }
            s += x[(size_t)c0.y * D + f]; s += x[(size_t)c1.y * D + f];
            s += x[(size_t)c2.y * D + f]; s += x[(size_t)c3.y * D + f];
            s += x[(size_t)c4.y * D + f]; s += x[(size_t)c5.y * D + f];
            s += x[(size_t)c6.y * D + f]; s += x[(size_t)c7.y * D + f];
            ax += ea[(size_t)(lo ? c0.x : c1.x) * ED + fe];
            ax += ea[(size_t)(lo ? c2.x : c3.x) * ED + fe];
            ay += ea[(size_t)(lo ? c4.x : c5.x) * ED + fe];
            ay += ea[(size_t)(lo ? c6.x : c7.x) * ED + fe];
            it += 8;
        }
        for (; it < n; ++it) {               // tail: 0..7 edges
            const int2 p = sp[it];
            s += x[(size_t)p.y * D + f];
            if (lo) ax += ea[(size_t)p.x * ED + fe];
        }
        pre[(size_t)node * D + f] = s;
        ax += ay;
        ax += __shfl_xor(ax, 32);            // even-edge + odd-edge halves
        if (lo) aggEA[(size_t)node * ED + fe] = ax;
    }
}

// ---------------------------------------------------------------------------
// MLP1 as tiled GEMM: h[64n x 64f] = [pre|aggEA] @ [W1;Wc] + deg*bec + b1.
// Every dynamic index targets LDS (spill-proof). 4x4 accs per thread.
// BN stats fused in epilogue.
__global__ __launch_bounds__(256) void mlp1g_kernel(
    const float* __restrict__ pre, const float* __restrict__ aggEA,
    const int* __restrict__ off,
    const float* __restrict__ W1, const float* __restrict__ wc,
    const float* __restrict__ bec, const float* __restrict__ b1,
    float* __restrict__ h, float* __restrict__ sums, float* __restrict__ sumsq)
{
    __shared__ float As[64 * 100];   // [node][k] k:0-63 pre, 64-95 aggEA; pad->2-way max
    __shared__ float Bs[96 * 64];    // [k][f]
    __shared__ float4 sb1v[16];
    __shared__ float4 sbecv[16];
    __shared__ float sDeg[64];
    const int tid = threadIdx.x;
    const int base = blockIdx.x * 64;

    for (int i = tid; i < 64 * 16; i += 256)            // W1 -> Bs rows 0..63
        ((float4*)Bs)[i] = ((const float4*)W1)[i];
    for (int i = tid; i < 32 * 16; i += 256)            // wc -> Bs rows 64..95
        ((float4*)Bs)[64 * 16 + i] = ((const float4*)wc)[i];
    if (tid < 16)      sb1v[tid] = ((const float4*)b1)[tid];
    else if (tid < 32) sbecv[tid - 16] = ((const float4*)bec)[tid - 16];
    if (tid < 64) {
        const int node = base + tid;
        sDeg[tid] = (node < N_NODES) ? (float)(off[node + 1] - off[node]) : 0.f;
    }
    #pragma unroll
    for (int r = 0; r < 4; ++r) {                       // pre -> As[nl][0..63]
        const int idx = tid + 256 * r;
        const int nl = idx >> 4, c4 = idx & 15;
        const bool v = (base + nl) < N_NODES;
        const float4 t = v ? ((const float4*)pre)[(size_t)(base + nl) * 16 + c4]
                           : make_float4(0.f, 0.f, 0.f, 0.f);
        *(float4*)&As[nl * 100 + c4 * 4] = t;
    }
    #pragma unroll
    for (int r = 0; r < 2; ++r) {                       // aggEA -> As[nl][64..95]
        const int idx = tid + 256 * r;
        const int nl = idx >> 3, c4 = idx & 7;
        const bool v = (base + nl) < N_NODES;
        const float4 t = v ? ((const float4*)aggEA)[(size_t)(base + nl) * 8 + c4]
                           : make_float4(0.f, 0.f, 0.f, 0.f);
        *(float4*)&As[nl * 100 + 64 + c4 * 4] = t;
    }
    __syncthreads();

    const int tx = tid & 15, ty = tid >> 4;
    const int r0 = ty * 4;
    const float4 bb = sb1v[tx];
    const float4 bc = sbecv[tx];
    float4 acc0, acc1, acc2, acc3;
    acc0.x = bb.x + sDeg[r0+0]*bc.x; acc0.y = bb.y + sDeg[r0+0]*bc.y;
    acc0.z = bb.z + sDeg[r0+0]*bc.z; acc0.w = bb.w + sDeg[r0+0]*bc.w;
    acc1.x = bb.x + sDeg[r0+1]*bc.x; acc1.y = bb.y + sDeg[r0+1]*bc.y;
    acc1.z = bb.z + sDeg[r0+1]*bc.z; acc1.w = bb.w + sDeg[r0+1]*bc.w;
    acc2.x = bb.x + sDeg[r0+2]*bc.x; acc2.y = bb.y + sDeg[r0+2]*bc.y;
    acc2.z = bb.z + sDeg[r0+2]*bc.z; acc2.w = bb.w + sDeg[r0+2]*bc.w;
    acc3.x = bb.x + sDeg[r0+3]*bc.x; acc3.y = bb.y + sDeg[r0+3]*bc.y;
    acc3.z = bb.z + sDeg[r0+3]*bc.z; acc3.w = bb.w + sDeg[r0+3]*bc.w;

    for (int k4 = 0; k4 < 24; ++k4) {
        const int k = k4 * 4;
        const float4 a0 = *(const float4*)&As[(r0+0)*100 + k];
        const float4 a1 = *(const float4*)&As[(r0+1)*100 + k];
        const float4 a2 = *(const float4*)&As[(r0+2)*100 + k];
        const float4 a3 = *(const float4*)&As[(r0+3)*100 + k];
        const float4 w0 = *(const float4*)&Bs[(k+0)*64 + tx*4];
        const float4 w1v = *(const float4*)&Bs[(k+1)*64 + tx*4];
        const float4 w2v = *(const float4*)&Bs[(k+2)*64 + tx*4];
        const float4 w3v = *(const float4*)&Bs[(k+3)*64 + tx*4];
        acc0.x += a0.x*w0.x + a0.y*w1v.x + a0.z*w2v.x + a0.w*w3v.x;
        acc0.y += a0.x*w0.y + a0.y*w1v.y + a0.z*w2v.y + a0.w*w3v.y;
        acc0.z += a0.x*w0.z + a0.y*w1v.z + a0.z*w2v.z + a0.w*w3v.z;
        acc0.w += a0.x*w0.w + a0.y*w1v.w + a0.z*w2v.w + a0.w*w3v.w;
        acc1.x += a1.x*w0.x + a1.y*w1v.x + a1.z*w2v.x + a1.w*w3v.x;
        acc1.y += a1.x*w0.y + a1.y*w1v.y + a1.z*w2v.y + a1.w*w3v.y;
        acc1.z += a1.x*w0.z + a1.y*w1v.z + a1.z*w2v.z + a1.w*w3v.z;
        acc1.w += a1.x*w0.w + a1.y*w1v.w + a1.z*w2v.w + a1.w*w3v.w;
        acc2.x += a2.x*w0.x + a2.y*w1v.x + a2.z*w2v.x + a2.w*w3v.x;
        acc2.y += a2.x*w0.y + a2.y*w1v.y + a2.z*w2v.y + a2.w*w3v.y;
        acc2.z += a2.x*w0.z + a2.y*w1v.z + a2.z*w2v.z + a2.w*w3v.z;
        acc2.w += a2.x*w0.w + a2.y*w1v.w + a2.z*w2v.w + a2.w*w3v.w;
        acc3.x += a3.x*w0.x + a3.y*w1v.x + a3.z*w2v.x + a3.w*w3v.x;
        acc3.y += a3.x*w0.y + a3.y*w1v.y + a3.z*w2v.y + a3.w*w3v.y;
        acc3.z += a3.x*w0.z + a3.y*w1v.z + a3.z*w2v.z + a3.w*w3v.z;
        acc3.w += a3.x*w0.w + a3.y*w1v.w + a3.z*w2v.w + a3.w*w3v.w;
    }

    float4 ps = make_float4(0.f, 0.f, 0.f, 0.f);
    float4 pq = make_float4(0.f, 0.f, 0.f, 0.f);
    {
        const int n0 = base + r0;
        if (n0 + 0 < N_NODES) {
            ((float4*)h)[(size_t)(n0+0)*16 + tx] = acc0;
            ps.x += acc0.x; ps.y += acc0.y; ps.z += acc0.z; ps.w += acc0.w;
            pq.x += acc0.x*acc0.x; pq.y += acc0.y*acc0.y;
            pq.z += acc0.z*acc0.z; pq.w += acc0.w*acc0.w;
        }
        if (n0 + 1 < N_NODES) {
            ((float4*)h)[(size_t)(n0+1)*16 + tx] = acc1;
            ps.x += acc1.x; ps.y += acc1.y; ps.z += acc1.z; ps.w += acc1.w;
            pq.x += acc1.x*acc1.x; pq.y += acc1.y*acc1.y;
            pq.z += acc1.z*acc1.z; pq.w += acc1.w*acc1.w;
        }
        if (n0 + 2 < N_NODES) {
            ((float4*)h)[(size_t)(n0+2)*16 + tx] = acc2;
            ps.x += acc2.x; ps.y += acc2.y; ps.z += acc2.z; ps.w += acc2.w;
            pq.x += acc2.x*acc2.x; pq.y += acc2.y*acc2.y;
            pq.z += acc2.z*acc2.z; pq.w += acc2.w*acc2.w;
        }
        if (n0 + 3 < N_NODES) {
            ((float4*)h)[(size_t)(n0+3)*16 + tx] = acc3;
            ps.x += acc3.x; ps.y += acc3.y; ps.z += acc3.z; ps.w += acc3.w;
            pq.x += acc3.x*acc3.x; pq.y += acc3.y*acc3.y;
            pq.z += acc3.z*acc3.z; pq.w += acc3.w*acc3.w;
        }
    }
    __syncthreads();
    float* sS = Bs;                 // reuse B-tile LDS for BN reduction
    float* sQ = Bs + 1024;
    sS[ty*64 + tx*4 + 0] = ps.x; sS[ty*64 + tx*4 + 1] = ps.y;
    sS[ty*64 + tx*4 + 2] = ps.z; sS[ty*64 + tx*4 + 3] = ps.w;
    sQ[ty*64 + tx*4 + 0] = pq.x; sQ[ty*64 + tx*4 + 1] = pq.y;
    sQ[ty*64 + tx*4 + 2] = pq.z; sQ[ty*64 + tx*4 + 3] = pq.w;
    __syncthreads();
    if (tid < 64) {
        float s = 0.f, q = 0.f;
        #pragma unroll
        for (int r = 0; r < 16; ++r) { s += sS[r*64 + tid]; q += sQ[r*64 + tid]; }
        unsafeAtomicAdd(&sums[tid], s);
        unsafeAtomicAdd(&sumsq[tid], q);
    }
}

// ---------------------------------------------------------------------------
// MLP2 as tiled GEMM: out = relu(h*sc+sh) @ W2 + b2 (BN applied at A-staging)
__global__ __launch_bounds__(256) void mlp2g_kernel(
    const float* __restrict__ h, const float* __restrict__ W2,
    const float* __restrict__ b2, const float* __restrict__ sums,
    const float* __restrict__ sumsq, const float* __restrict__ gamma,
    const float* __restrict__ beta, float* __restrict__ out)
{
    __shared__ float As[64 * 68];
    __shared__ float Bs[64 * 64];
    __shared__ float4 sb2v[16];
    __shared__ float4 sscv[16];
    __shared__ float4 sshv[16];
    const int tid = threadIdx.x;
    const int base = blockIdx.x * 64;

    for (int i = tid; i < 64 * 16; i += 256)
        ((float4*)Bs)[i] = ((const float4*)W2)[i];
    if (tid < 16) sb2v[tid] = ((const float4*)b2)[tid];
    if (tid < 64) {
        const float inv_n = 1.0f / (float)N_NODES;
        const float mean = sums[tid] * inv_n;
        const float var  = sumsq[tid] * inv_n - mean * mean;   // biased, like jnp.var
        const float sc   = gamma[tid] * rsqrtf(var + BN_EPS);
        ((float*)sscv)[tid] = sc;
        ((float*)sshv)[tid] = beta[tid] - mean * sc;
    }
    __syncthreads();                 // sscv/sshv needed by A-staging

    #pragma unroll
    for (int r = 0; r < 4; ++r) {
        const int idx = tid + 256 * r;
        const int nl = idx >> 4, c4 = idx & 15;
        const bool v = (base + nl) < N_NODES;
        const float4 t = v ? ((const float4*)h)[(size_t)(base + nl) * 16 + c4]
                           : make_float4(0.f, 0.f, 0.f, 0.f);
        const float4 c = sscv[c4];
        const float4 s = sshv[c4];
        float4 rv;
        rv.x = fmaxf(t.x * c.x + s.x, 0.f);
        rv.y = fmaxf(t.y * c.y + s.y, 0.f);
        rv.z = fmaxf(t.z * c.z + s.z, 0.f);
        rv.w = fmaxf(t.w * c.w + s.w, 0.f);
        *(float4*)&As[nl * 68 + c4 * 4] = rv;
    }
    __syncthreads();

    const int tx = tid & 15, ty = tid >> 4;
    const int r0 = ty * 4;
    const float4 bb = sb2v[tx];
    float4 acc0 = bb, acc1 = bb, acc2 = bb, acc3 = bb;

    for (int k4 = 0; k4 < 16; ++k4) {
        const int k = k4 * 4;
        const float4 a0 = *(const float4*)&As[(r0+0)*68 + k];
        const float4 a1 = *(const float4*)&As[(r0+1)*68 + k];
        const float4 a2 = *(const float4*)&As[(r0+2)*68 + k];
        const float4 a3 = *(const float4*)&As[(r0+3)*68 + k];
        const float4 w0 = *(const float4*)&Bs[(k+0)*64 + tx*4];
        const float4 w1v = *(const float4*)&Bs[(k+1)*64 + tx*4];
        const float4 w2v = *(const float4*)&Bs[(k+2)*64 + tx*4];
        const float4 w3v = *(const float4*)&Bs[(k+3)*64 + tx*4];
        acc0.x += a0.x*w0.x + a0.y*w1v.x + a0.z*w2v.x + a0.w*w3v.x;
        acc0.y += a0.x*w0.y + a0.y*w1v.y + a0.z*w2v.y + a0.w*w3v.y;
        acc0.z += a0.x*w0.z + a0.y*w1v.z + a0.z*w2v.z + a0.w*w3v.z;
        acc0.w += a0.x*w0.w + a0.y*w1v.w + a0.z*w2v.w + a0.w*w3v.w;
        acc1.x += a1.x*w0.x + a1.y*w1v.x + a1.z*w2v.x + a1.w*w3v.x;
        acc1.y += a1.x*w0.y + a1.y*w1v.y + a1.z*w2v.y + a1.w*w3v.y;
        acc1.z += a1.x*w0.z + a1.y*w1v.z + a1.z*w2v.z + a1.w*w3v.z;
        acc1.w += a1.x*w0.w + a1.y*w1v.w + a1.z*w2v.w + a1.w*w3v.w;
        acc2.x += a2.x*w0.x + a2.y*w1v.x + a2.z*w2v.x + a2.w*w3v.x;
        acc2.y += a2.x*w0.y + a2.y*w1v.y + a2.z*w2v.y + a2.w*w3v.y;
        acc2.z += a2.x*w0.z + a2.y*w1v.z + a2.z*w2v.z + a2.w*w3v.z;
        acc2.w += a2.x*w0.w + a2.y*w1v.w + a2.z*w2v.w + a2.w*w3v.w;
        acc3.x += a3.x*w0.x + a3.y*w1v.x + a3.z*w2v.x + a3.w*w3v.x;
        acc3.y += a3.x*w0.y + a3.y*w1v.y + a3.z*w2v.y + a3.w*w3v.y;
        acc3.z += a3.x*w0.z + a3.y*w1v.z + a3.z*w2v.z + a3.w*w3v.z;
        acc3.w += a3.x*w0.w + a3.y*w1v.w + a3.z*w2v.w + a3.w*w3v.w;
    }

    const int n0 = base + r0;
    if (n0 + 0 < N_NODES) ((float4*)out)[(size_t)(n0+0)*16 + tx] = acc0;
    if (n0 + 1 < N_NODES) ((float4*)out)[(size_t)(n0+1)*16 + tx] = acc1;
    if (n0 + 2 < N_NODES) ((float4*)out)[(size_t)(n0+2)*16 + tx] = acc2;
    if (n0 + 3 < N_NODES) ((float4*)out)[(size_t)(n0+3)*16 + tx] = acc3;
}

// ---------------------------------------------------------------------------
extern "C" void kernel_launch(void* const* d_in, const int* in_sizes, int n_in,
                              void* d_out, int out_size, void* d_ws, size_t ws_size,
                              hipStream_t stream) {
    const float* x     = (const float*)d_in[0];
    const int*   ei    = (const int*)  d_in[1];   // [2, E] int32
    const float* ea    = (const float*)d_in[2];
    const float* We    = (const float*)d_in[3];
    const float* be    = (const float*)d_in[4];
    const float* W1    = (const float*)d_in[5];
    const float* b1    = (const float*)d_in[6];
    const float* gamma = (const float*)d_in[7];
    const float* beta  = (const float*)d_in[8];
    const float* W2    = (const float*)d_in[9];
    const float* b2    = (const float*)d_in[10];

    float* ws      = (float*)d_ws;
    float* sums    = ws + WS_SUMS;
    float* sumsq   = ws + WS_SUMSQ;
    int*   partial = (int*)(ws + WS_PART);
    int*   deg     = (int*)(ws + WS_DEG);
    int*   off     = (int*)(ws + WS_OFF);
    int*   cursor  = (int*)(ws + WS_CURSOR);
    int2*  sorted2 = (int2*)(ws + WS_SRC2);
    float* aggEA   = ws + WS_AGGEA;
    float* pre     = ws + WS_PRE;
    float* h       = ws + WS_H;
    float* wcbuf   = ws + WS_WC;
    float* becbuf  = ws + WS_BEC;

    hipMemsetAsync(ws, 0, (size_t)WS_ZERO_END * sizeof(float), stream);

    foldw_kernel       <<<8, 256, 0, stream>>>(We, W1, be, wcbuf, becbuf);
    count_kernel       <<<784, 256, 0, stream>>>(ei + N_EDGES, deg);
    scan_partial_kernel<<<SCAN_BLOCKS, 256, 0, stream>>>(deg, partial);
    scan_write_kernel  <<<SCAN_BLOCKS, 256, 0, stream>>>(deg, partial, off, cursor);
    scatter_kernel     <<<1024, 256, 0, stream>>>(ei, cursor, sorted2);
    agg_kernel         <<<2048, 256, 0, stream>>>(x, ea, off, sorted2, pre, aggEA);
    mlp1g_kernel       <<<N_BLK, 256, 0, stream>>>(pre, aggEA, off, W1, wcbuf,
                                                   becbuf, b1, h, sums, sumsq);
    mlp2g_kernel       <<<N_BLK, 256, 0, stream>>>(h, W2, b2, sums, sumsq,
                                                   gamma, beta, (float*)d_out);
}

// Round 8
// 313.029 us; speedup vs baseline: 1.3454x; 1.1338x over previous
//
#include <hip/hip_runtime.h>

#define N_NODES 50000
#define N_EDGES 800000
#define D 64          // D_IN == D_OUT
#define ED 32         // EDGE_DIM
#define BN_EPS 1e-5f

#define NBKT 100      // buckets
#define NPB  500      // nodes per bucket (100*500 = 50000)
#define EPB  3125     // edges per bin block (256*3125 = 800000)

// ---- workspace layout (32-bit word indices) -------------------------------
#define WS_SUMS     0
#define WS_SUMSQ    64
#define WS_BTOT     128                       // 128 ints (100 used)
#define WS_RESV     256                       // 128 ints (100 used)
#define WS_ZERO_END 384                       // memset [0, here) = 1.5 KB
#define WS_OFF      384                       // 50004 ints
#define WS_PACK     50388                     // uint2 x 800k (byte 201552, 8B ok)
#define WS_SRC2     (WS_PACK + 2 * N_EDGES)   // 1650388 (byte 6601552, 8B ok)
#define WS_AGGEA    (WS_SRC2 + 2 * N_EDGES)   // 3250388 (byte 13001552, 16B ok)
#define WS_PRE      (WS_AGGEA + N_NODES * ED) // 4850388 (byte 19401552, 16B ok)
#define WS_H        (WS_PRE + N_NODES * D)    // 8050388 (byte 32201552, 16B ok)
#define WS_WC       (WS_H + N_NODES * D)      // 11250388 (byte 45001552, 16B ok)
#define WS_BEC      (WS_WC + ED * D)          // 11252436
// total ~ 45 MB (ws proved >= 68 MB)

#define N_BLK ((N_NODES + 63) / 64)   // 782 GEMM tiles

// ---------------------------------------------------------------------------
// Fold edge MLP into main GEMM: wc = We@W1 [32x64], bec = be@W1 [64]
__global__ __launch_bounds__(256) void foldw_kernel(
    const float* __restrict__ We, const float* __restrict__ W1,
    const float* __restrict__ be, float* __restrict__ wc, float* __restrict__ bec)
{
    const int idx = blockIdx.x * 256 + threadIdx.x;
    if (idx < ED * D) {
        const int j = idx >> 6, f = idx & 63;
        float a = 0.f;
        for (int k = 0; k < D; ++k) a += We[j * D + k] * W1[k * D + f];
        wc[idx] = a;
    }
    if (idx < D) {
        float a = 0.f;
        for (int k = 0; k < D; ++k) a += be[k] * W1[k * D + idx];
        bec[idx] = a;
    }
}

// ---------------------------------------------------------------------------
// Pass 1: per-block LDS histogram of dst buckets -> global bucket totals
__global__ __launch_bounds__(256) void bin_hist_kernel(
    const int* __restrict__ dst, int* __restrict__ btot)
{
    __shared__ int hist[NBKT];
    const int t = threadIdx.x;
    if (t < NBKT) hist[t] = 0;
    __syncthreads();
    const int e0 = blockIdx.x * EPB;
    for (int i = t; i < EPB; i += 256)
        atomicAdd(&hist[dst[e0 + i] / NPB], 1);
    __syncthreads();
    if (t < NBKT) atomicAdd(&btot[t], hist[t]);
}

// ---------------------------------------------------------------------------
// Pass 2: bucket-grouped scatter with per-(block,bucket) contiguous segments.
// Each block: in-block scan of btot -> bucket bases; LDS hist of its chunk;
// ONE global atomic per bucket reserves a contiguous segment; packed writes
// land in 248B-average runs (no 64B-line amplification).
__global__ __launch_bounds__(256) void bin_scatter_kernel(
    const int* __restrict__ ei, const int* __restrict__ btot,
    int* __restrict__ resv, uint2* __restrict__ pack)
{
    __shared__ int sA[128], sB[128];
    __shared__ int bb[NBKT];                  // exclusive bucket bases
    __shared__ int hist[NBKT], seg[NBKT], lcur[NBKT];
    const int t = threadIdx.x;
    if (t < NBKT) { hist[t] = 0; lcur[t] = 0; }
    if (t < 128) sA[t] = (t < NBKT) ? btot[t] : 0;
    __syncthreads();
    int* cur = sA; int* nxt = sB;
    for (int o = 1; o < 128; o <<= 1) {       // inclusive scan of 128
        if (t < 128) nxt[t] = cur[t] + (t >= o ? cur[t - o] : 0);
        __syncthreads();
        int* tmp = cur; cur = nxt; nxt = tmp;
    }
    if (t < NBKT) bb[t] = (t == 0) ? 0 : cur[t - 1];
    __syncthreads();

    const int e0 = blockIdx.x * EPB;
    for (int i = t; i < EPB; i += 256)        // phase A: chunk histogram
        atomicAdd(&hist[ei[N_EDGES + e0 + i] / NPB], 1);
    __syncthreads();
    if (t < NBKT) seg[t] = bb[t] + atomicAdd(&resv[t], hist[t]);
    __syncthreads();
    for (int i = t; i < EPB; i += 256) {      // phase C: place into segment
        const int e = e0 + i;
        const int s = ei[e];
        const int d = ei[N_EDGES + e];
        const int bkt = d / NPB;
        const int r = atomicAdd(&lcur[bkt], 1);
        pack[seg[bkt] + r] = make_uint2(((unsigned)d << 16) | (unsigned)s,
                                        (unsigned)e);
    }
}

// ---------------------------------------------------------------------------
// Pass 3: one block per bucket. LDS per-node histogram + scan -> off[] (also
// replaces the old count/scan kernels); then final placement. All writes in a
// ~64KB single-XCD region -> L2 assembles full lines.
__global__ __launch_bounds__(256) void bucket_place_kernel(
    const int* __restrict__ btot, const uint2* __restrict__ pack,
    int* __restrict__ off, int2* __restrict__ sorted)
{
    __shared__ int sA[128], sB[128];
    __shared__ int cnt[NPB], lcur[NPB];
    __shared__ int pA[512], pB[512];
    __shared__ int sBase, sNE;
    const int t = threadIdx.x;
    const int j = blockIdx.x;
    if (t < 128) sA[t] = (t < NBKT) ? btot[t] : 0;
    for (int i = t; i < NPB; i += 256) { cnt[i] = 0; lcur[i] = 0; }
    __syncthreads();
    int* cur = sA; int* nxt = sB;
    for (int o = 1; o < 128; o <<= 1) {       // bucket bases
        if (t < 128) nxt[t] = cur[t] + (t >= o ? cur[t - o] : 0);
        __syncthreads();
        int* tmp = cur; cur = nxt; nxt = tmp;
    }
    if (t == 0) { sBase = (j == 0) ? 0 : cur[j - 1]; sNE = btot[j]; }
    __syncthreads();
    const int base = sBase, nE = sNE;
    const uint2* pp = pack + base;

    for (int i = t; i < nE; i += 256)         // per-node histogram
        atomicAdd(&cnt[(int)(pp[i].x >> 16) - j * NPB], 1);
    __syncthreads();
    for (int i = t; i < 512; i += 256) pA[i] = (i < NPB) ? cnt[i] : 0;
    __syncthreads();
    int* c2 = pA; int* n2 = pB;
    for (int o = 1; o < 512; o <<= 1) {       // inclusive scan of 512
        for (int i = t; i < 512; i += 256)
            n2[i] = c2[i] + (i >= o ? c2[i - o] : 0);
        __syncthreads();
        int* tmp = c2; c2 = n2; n2 = tmp;
    }
    for (int i = t; i < NPB; i += 256) {      // n2 := exclusive starts; off[]
        const int excl = (i == 0) ? 0 : c2[i - 1];
        n2[i] = excl;
        off[j * NPB + i] = base + excl;
    }
    if (j == NBKT - 1 && t == 0) off[N_NODES] = N_EDGES;
    __syncthreads();
    for (int i = t; i < nE; i += 256) {       // final placement
        const uint2 w = pp[i];
        const int dl = (int)(w.x >> 16) - j * NPB;
        const int r = atomicAdd(&lcur[dl], 1);
        sorted[base + n2[dl] + r] = make_int2((int)w.y, (int)(w.x & 0xffffu));
    }
}

// ---------------------------------------------------------------------------
// Pure gather, no LDS -> full occupancy. Per node (wave):
//   pre[node]   = x[node] + sum_e x[src[e]]        (256B rows, lanes 0..63)
//   aggEA[node] = sum_e ea[eid[e]]                 (128B rows, 2 edges/instr)
__global__ __launch_bounds__(256) void agg_kernel(
    const float* __restrict__ x, const float* __restrict__ ea,
    const int* __restrict__ off, const int2* __restrict__ sorted,
    float* __restrict__ pre, float* __restrict__ aggEA)
{
    const int f = threadIdx.x & 63;
    const int w = threadIdx.x >> 6;
    const int fe = f & 31;
    const bool lo = (f < 32);
    const int nwv = gridDim.x * 4;
    for (int node = blockIdx.x * 4 + w; node < N_NODES; node += nwv) {
        const int start = __builtin_amdgcn_readfirstlane(off[node]);
        const int n     = __builtin_amdgcn_readfirstlane(off[node + 1]) - start;
        const int2* sp = sorted + start;
        float s = x[(size_t)node * D + f];
        float ax = 0.f, ay = 0.f;
        int it = 0;
        if (n >= 8) {
            int2 c0 = sp[0], c1 = sp[1], c2 = sp[2], c3 = sp[3];
            int2 c4 = sp[4], c5 = sp[5], c6 = sp[6], c7 = sp[7];
            for (; it + 16 <= n; it += 8) {
                const int2 n0 = sp[it + 8],  n1 = sp[it + 9];
                const int2 n2 = sp[it + 10], n3 = sp[it + 11];
                const int2 n4 = sp[it + 12], n5 = sp[it + 13];
                const int2 n6 = sp[it + 14], n7 = sp[it + 15];
                s += x[(size_t)c0.y * D + f]; s += x[(size_t)c1.y * D + f];
                s += x[(size_t)c2.y * D + f]; s += x[(size_t)c3.y * D + f];
                s += x[(size_t)c4.y * D + f]; s += x[(size_t)c5.y * D + f];
                s += x[(size_t)c6.y * D + f]; s += x[(size_t)c7.y * D + f];
                ax += ea[(size_t)(lo ? c0.x : c1.x) * ED + fe];
                ax += ea[(size_t)(lo ? c2.x : c3.x) * ED + fe];
                ay += ea[(size_t)(lo ? c4.x : c5.x) * ED + fe];
                ay += ea[(size_t)(lo ? c6.x : c7.x) * ED + fe];
                c0 = n0; c1 = n1; c2 = n2; c3 = n3;
                c4 = n4; c5 = n5; c6 = n6; c7 = n7;
            }
            s += x[(size_t)c0.y * D + f]; s += x[(size_t)c1.y * D + f];
            s += x[(size_t)c2.y * D + f]; s += x[(size_t)c3.y * D + f];
            s += x[(size_t)c4.y * D + f]; s += x[(size_t)c5.y * D + f];
            s += x[(size_t)c6.y * D + f]; s += x[(size_t)c7.y * D + f];
            ax += ea[(size_t)(lo ? c0.x : c1.x) * ED + fe];
            ax += ea[(size_t)(lo ? c2.x : c3.x) * ED + fe];
            ay += ea[(size_t)(lo ? c4.x : c5.x) * ED + fe];
            ay += ea[(size_t)(lo ? c6.x : c7.x) * ED + fe];
            it += 8;
        }
        for (; it < n; ++it) {               // tail: 0..7 edges
            const int2 p = sp[it];
            s += x[(size_t)p.y * D + f];
            if (lo) ax += ea[(size_t)p.x * ED + fe];
        }
        pre[(size_t)node * D + f] = s;
        ax += ay;
        ax += __shfl_xor(ax, 32);            // even-edge + odd-edge halves
        if (lo) aggEA[(size_t)node * ED + fe] = ax;
    }
}

// ---------------------------------------------------------------------------
// MLP1 as tiled GEMM: h[64n x 64f] = [pre|aggEA] @ [W1;Wc] + deg*bec + b1.
// Every dynamic index targets LDS (spill-proof). BN stats fused in epilogue.
__global__ __launch_bounds__(256) void mlp1g_kernel(
    const float* __restrict__ pre, const float* __restrict__ aggEA,
    const int* __restrict__ off,
    const float* __restrict__ W1, const float* __restrict__ wc,
    const float* __restrict__ bec, const float* __restrict__ b1,
    float* __restrict__ h, float* __restrict__ sums, float* __restrict__ sumsq)
{
    __shared__ float As[64 * 100];   // [node][k] k:0-63 pre, 64-95 aggEA
    __shared__ float Bs[96 * 64];    // [k][f]
    __shared__ float4 sb1v[16];
    __shared__ float4 sbecv[16];
    __shared__ float sDeg[64];
    const int tid = threadIdx.x;
    const int base = blockIdx.x * 64;

    for (int i = tid; i < 64 * 16; i += 256)
        ((float4*)Bs)[i] = ((const float4*)W1)[i];
    for (int i = tid; i < 32 * 16; i += 256)
        ((float4*)Bs)[64 * 16 + i] = ((const float4*)wc)[i];
    if (tid < 16)      sb1v[tid] = ((const float4*)b1)[tid];
    else if (tid < 32) sbecv[tid - 16] = ((const float4*)bec)[tid - 16];
    if (tid < 64) {
        const int node = base + tid;
        sDeg[tid] = (node < N_NODES) ? (float)(off[node + 1] - off[node]) : 0.f;
    }
    #pragma unroll
    for (int r = 0; r < 4; ++r) {
        const int idx = tid + 256 * r;
        const int nl = idx >> 4, c4 = idx & 15;
        const bool v = (base + nl) < N_NODES;
        const float4 t = v ? ((const float4*)pre)[(size_t)(base + nl) * 16 + c4]
                           : make_float4(0.f, 0.f, 0.f, 0.f);
        *(float4*)&As[nl * 100 + c4 * 4] = t;
    }
    #pragma unroll
    for (int r = 0; r < 2; ++r) {
        const int idx = tid + 256 * r;
        const int nl = idx >> 3, c4 = idx & 7;
        const bool v = (base + nl) < N_NODES;
        const float4 t = v ? ((const float4*)aggEA)[(size_t)(base + nl) * 8 + c4]
                           : make_float4(0.f, 0.f, 0.f, 0.f);
        *(float4*)&As[nl * 100 + 64 + c4 * 4] = t;
    }
    __syncthreads();

    const int tx = tid & 15, ty = tid >> 4;
    const int r0 = ty * 4;
    const float4 bb = sb1v[tx];
    const float4 bc = sbecv[tx];
    float4 acc0, acc1, acc2, acc3;
    acc0.x = bb.x + sDeg[r0+0]*bc.x; acc0.y = bb.y + sDeg[r0+0]*bc.y;
    acc0.z = bb.z + sDeg[r0+0]*bc.z; acc0.w = bb.w + sDeg[r0+0]*bc.w;
    acc1.x = bb.x + sDeg[r0+1]*bc.x; acc1.y = bb.y + sDeg[r0+1]*bc.y;
    acc1.z = bb.z + sDeg[r0+1]*bc.z; acc1.w = bb.w + sDeg[r0+1]*bc.w;
    acc2.x = bb.x + sDeg[r0+2]*bc.x; acc2.y = bb.y + sDeg[r0+2]*bc.y;
    acc2.z = bb.z + sDeg[r0+2]*bc.z; acc2.w = bb.w + sDeg[r0+2]*bc.w;
    acc3.x = bb.x + sDeg[r0+3]*bc.x; acc3.y = bb.y + sDeg[r0+3]*bc.y;
    acc3.z = bb.z + sDeg[r0+3]*bc.z; acc3.w = bb.w + sDeg[r0+3]*bc.w;

    for (int k4 = 0; k4 < 24; ++k4) {
        const int k = k4 * 4;
        const float4 a0 = *(const float4*)&As[(r0+0)*100 + k];
        const float4 a1 = *(const float4*)&As[(r0+1)*100 + k];
        const float4 a2 = *(const float4*)&As[(r0+2)*100 + k];
        const float4 a3 = *(const float4*)&As[(r0+3)*100 + k];
        const float4 w0 = *(const float4*)&Bs[(k+0)*64 + tx*4];
        const float4 w1v = *(const float4*)&Bs[(k+1)*64 + tx*4];
        const float4 w2v = *(const float4*)&Bs[(k+2)*64 + tx*4];
        const float4 w3v = *(const float4*)&Bs[(k+3)*64 + tx*4];
        acc0.x += a0.x*w0.x + a0.y*w1v.x + a0.z*w2v.x + a0.w*w3v.x;
        acc0.y += a0.x*w0.y + a0.y*w1v.y + a0.z*w2v.y + a0.w*w3v.y;
        acc0.z += a0.x*w0.z + a0.y*w1v.z + a0.z*w2v.z + a0.w*w3v.z;
        acc0.w += a0.x*w0.w + a0.y*w1v.w + a0.z*w2v.w + a0.w*w3v.w;
        acc1.x += a1.x*w0.x + a1.y*w1v.x + a1.z*w2v.x + a1.w*w3v.x;
        acc1.y += a1.x*w0.y + a1.y*w1v.y + a1.z*w2v.y + a1.w*w3v.y;
        acc1.z += a1.x*w0.z + a1.y*w1v.z + a1.z*w2v.z + a1.w*w3v.z;
        acc1.w += a1.x*w0.w + a1.y*w1v.w + a1.z*w2v.w + a1.w*w3v.w;
        acc2.x += a2.x*w0.x + a2.y*w1v.x + a2.z*w2v.x + a2.w*w3v.x;
        acc2.y += a2.x*w0.y + a2.y*w1v.y + a2.z*w2v.y + a2.w*w3v.y;
        acc2.z += a2.x*w0.z + a2.y*w1v.z + a2.z*w2v.z + a2.w*w3v.z;
        acc2.w += a2.x*w0.w + a2.y*w1v.w + a2.z*w2v.w + a2.w*w3v.w;
        acc3.x += a3.x*w0.x + a3.y*w1v.x + a3.z*w2v.x + a3.w*w3v.x;
        acc3.y += a3.x*w0.y + a3.y*w1v.y + a3.z*w2v.y + a3.w*w3v.y;
        acc3.z += a3.x*w0.z + a3.y*w1v.z + a3.z*w2v.z + a3.w*w3v.z;
        acc3.w += a3.x*w0.w + a3.y*w1v.w + a3.z*w2v.w + a3.w*w3v.w;
    }

    float4 ps = make_float4(0.f, 0.f, 0.f, 0.f);
    float4 pq = make_float4(0.f, 0.f, 0.f, 0.f);
    {
        const int n0 = base + r0;
        if (n0 + 0 < N_NODES) {
            ((float4*)h)[(size_t)(n0+0)*16 + tx] = acc0;
            ps.x += acc0.x; ps.y += acc0.y; ps.z += acc0.z; ps.w += acc0.w;
            pq.x += acc0.x*acc0.x; pq.y += acc0.y*acc0.y;
            pq.z += acc0.z*acc0.z; pq.w += acc0.w*acc0.w;
        }
        if (n0 + 1 < N_NODES) {
            ((float4*)h)[(size_t)(n0+1)*16 + tx] = acc1;
            ps.x += acc1.x; ps.y += acc1.y; ps.z += acc1.z; ps.w += acc1.w;
            pq.x += acc1.x*acc1.x; pq.y += acc1.y*acc1.y;
            pq.z += acc1.z*acc1.z; pq.w += acc1.w*acc1.w;
        }
        if (n0 + 2 < N_NODES) {
            ((float4*)h)[(size_t)(n0+2)*16 + tx] = acc2;
            ps.x += acc2.x; ps.y += acc2.y; ps.z += acc2.z; ps.w += acc2.w;
            pq.x += acc2.x*acc2.x; pq.y += acc2.y*acc2.y;
            pq.z += acc2.z*acc2.z; pq.w += acc2.w*acc2.w;
        }
        if (n0 + 3 < N_NODES) {
            ((float4*)h)[(size_t)(n0+3)*16 + tx] = acc3;
            ps.x += acc3.x; ps.y += acc3.y; ps.z += acc3.z; ps.w += acc3.w;
            pq.x += acc3.x*acc3.x; pq.y += acc3.y*acc3.y;
            pq.z += acc3.z*acc3.z; pq.w += acc3.w*acc3.w;
        }
    }
    __syncthreads();
    float* sS = Bs;                 // reuse B-tile LDS for BN reduction
    float* sQ = Bs + 1024;
    sS[ty*64 + tx*4 + 0] = ps.x; sS[ty*64 + tx*4 + 1] = ps.y;
    sS[ty*64 + tx*4 + 2] = ps.z; sS[ty*64 + tx*4 + 3] = ps.w;
    sQ[ty*64 + tx*4 + 0] = pq.x; sQ[ty*64 + tx*4 + 1] = pq.y;
    sQ[ty*64 + tx*4 + 2] = pq.z; sQ[ty*64 + tx*4 + 3] = pq.w;
    __syncthreads();
    if (tid < 64) {
        float s = 0.f, q = 0.f;
        #pragma unroll
        for (int r = 0; r < 16; ++r) { s += sS[r*64 + tid]; q += sQ[r*64 + tid]; }
        unsafeAtomicAdd(&sums[tid], s);
        unsafeAtomicAdd(&sumsq[tid], q);
    }
}

// ---------------------------------------------------------------------------
// MLP2 as tiled GEMM: out = relu(h*sc+sh) @ W2 + b2 (BN applied at A-staging)
__global__ __launch_bounds__(256) void mlp2g_kernel(
    const float* __restrict__ h, const float* __restrict__ W2,
    const float* __restrict__ b2, const float* __restrict__ sums,
    const float* __restrict__ sumsq, const float* __restrict__ gamma,
    const float* __restrict__ beta, float* __restrict__ out)
{
    __shared__ float As[64 * 68];
    __shared__ float Bs[64 * 64];
    __shared__ float4 sb2v[16];
    __shared__ float4 sscv[16];
    __shared__ float4 sshv[16];
    const int tid = threadIdx.x;
    const int base = blockIdx.x * 64;

    for (int i = tid; i < 64 * 16; i += 256)
        ((float4*)Bs)[i] = ((const float4*)W2)[i];
    if (tid < 16) sb2v[tid] = ((const float4*)b2)[tid];
    if (tid < 64) {
        const float inv_n = 1.0f / (float)N_NODES;
        const float mean = sums[tid] * inv_n;
        const float var  = sumsq[tid] * inv_n - mean * mean;   // biased, like jnp.var
        const float sc   = gamma[tid] * rsqrtf(var + BN_EPS);
        ((float*)sscv)[tid] = sc;
        ((float*)sshv)[tid] = beta[tid] - mean * sc;
    }
    __syncthreads();

    #pragma unroll
    for (int r = 0; r < 4; ++r) {
        const int idx = tid + 256 * r;
        const int nl = idx >> 4, c4 = idx & 15;
        const bool v = (base + nl) < N_NODES;
        const float4 t = v ? ((const float4*)h)[(size_t)(base + nl) * 16 + c4]
                           : make_float4(0.f, 0.f, 0.f, 0.f);
        const float4 c = sscv[c4];
        const float4 s = sshv[c4];
        float4 rv;
        rv.x = fmaxf(t.x * c.x + s.x, 0.f);
        rv.y = fmaxf(t.y * c.y + s.y, 0.f);
        rv.z = fmaxf(t.z * c.z + s.z, 0.f);
        rv.w = fmaxf(t.w * c.w + s.w, 0.f);
        *(float4*)&As[nl * 68 + c4 * 4] = rv;
    }
    __syncthreads();

    const int tx = tid & 15, ty = tid >> 4;
    const int r0 = ty * 4;
    const float4 bb = sb2v[tx];
    float4 acc0 = bb, acc1 = bb, acc2 = bb, acc3 = bb;

    for (int k4 = 0; k4 < 16; ++k4) {
        const int k = k4 * 4;
        const float4 a0 = *(const float4*)&As[(r0+0)*68 + k];
        const float4 a1 = *(const float4*)&As[(r0+1)*68 + k];
        const float4 a2 = *(const float4*)&As[(r0+2)*68 + k];
        const float4 a3 = *(const float4*)&As[(r0+3)*68 + k];
        const float4 w0 = *(const float4*)&Bs[(k+0)*64 + tx*4];
        const float4 w1v = *(const float4*)&Bs[(k+1)*64 + tx*4];
        const float4 w2v = *(const float4*)&Bs[(k+2)*64 + tx*4];
        const float4 w3v = *(const float4*)&Bs[(k+3)*64 + tx*4];
        acc0.x += a0.x*w0.x + a0.y*w1v.x + a0.z*w2v.x + a0.w*w3v.x;
        acc0.y += a0.x*w0.y + a0.y*w1v.y + a0.z*w2v.y + a0.w*w3v.y;
        acc0.z += a0.x*w0.z + a0.y*w1v.z + a0.z*w2v.z + a0.w*w3v.z;
        acc0.w += a0.x*w0.w + a0.y*w1v.w + a0.z*w2v.w + a0.w*w3v.w;
        acc1.x += a1.x*w0.x + a1.y*w1v.x + a1.z*w2v.x + a1.w*w3v.x;
        acc1.y += a1.x*w0.y + a1.y*w1v.y + a1.z*w2v.y + a1.w*w3v.y;
        acc1.z += a1.x*w0.z + a1.y*w1v.z + a1.z*w2v.z + a1.w*w3v.z;
        acc1.w += a1.x*w0.w + a1.y*w1v.w + a1.z*w2v.w + a1.w*w3v.w;
        acc2.x += a2.x*w0.x + a2.y*w1v.x + a2.z*w2v.x + a2.w*w3v.x;
        acc2.y += a2.x*w0.y + a2.y*w1v.y + a2.z*w2v.y + a2.w*w3v.y;
        acc2.z += a2.x*w0.z + a2.y*w1v.z + a2.z*w2v.z + a2.w*w3v.z;
        acc2.w += a2.x*w0.w + a2.y*w1v.w + a2.z*w2v.w + a2.w*w3v.w;
        acc3.x += a3.x*w0.x + a3.y*w1v.x + a3.z*w2v.x + a3.w*w3v.x;
        acc3.y += a3.x*w0.y + a3.y*w1v.y + a3.z*w2v.y + a3.w*w3v.y;
        acc3.z += a3.x*w0.z + a3.y*w1v.z + a3.z*w2v.z + a3.w*w3v.z;
        acc3.w += a3.x*w0.w + a3.y*w1v.w + a3.z*w2v.w + a3.w*w3v.w;
    }

    const int n0 = base + r0;
    if (n0 + 0 < N_NODES) ((float4*)out)[(size_t)(n0+0)*16 + tx] = acc0;
    if (n0 + 1 < N_NODES) ((float4*)out)[(size_t)(n0+1)*16 + tx] = acc1;
    if (n0 + 2 < N_NODES) ((float4*)out)[(size_t)(n0+2)*16 + tx] = acc2;
    if (n0 + 3 < N_NODES) ((float4*)out)[(size_t)(n0+3)*16 + tx] = acc3;
}

// ---------------------------------------------------------------------------
extern "C" void kernel_launch(void* const* d_in, const int* in_sizes, int n_in,
                              void* d_out, int out_size, void* d_ws, size_t ws_size,
                              hipStream_t stream) {
    const float* x     = (const float*)d_in[0];
    const int*   ei    = (const int*)  d_in[1];   // [2, E] int32
    const float* ea    = (const float*)d_in[2];
    const float* We    = (const float*)d_in[3];
    const float* be    = (const float*)d_in[4];
    const float* W1    = (const float*)d_in[5];
    const float* b1    = (const float*)d_in[6];
    const float* gamma = (const float*)d_in[7];
    const float* beta  = (const float*)d_in[8];
    const float* W2    = (const float*)d_in[9];
    const float* b2    = (const float*)d_in[10];

    float* ws      = (float*)d_ws;
    float* sums    = ws + WS_SUMS;
    float* sumsq   = ws + WS_SUMSQ;
    int*   btot    = (int*)(ws + WS_BTOT);
    int*   resv    = (int*)(ws + WS_RESV);
    int*   off     = (int*)(ws + WS_OFF);
    uint2* pack    = (uint2*)(ws + WS_PACK);
    int2*  sorted2 = (int2*)(ws + WS_SRC2);
    float* aggEA   = ws + WS_AGGEA;
    float* pre     = ws + WS_PRE;
    float* h       = ws + WS_H;
    float* wcbuf   = ws + WS_WC;
    float* becbuf  = ws + WS_BEC;

    hipMemsetAsync(ws, 0, (size_t)WS_ZERO_END * sizeof(float), stream);

    foldw_kernel       <<<8, 256, 0, stream>>>(We, W1, be, wcbuf, becbuf);
    bin_hist_kernel    <<<256, 256, 0, stream>>>(ei + N_EDGES, btot);
    bin_scatter_kernel <<<256, 256, 0, stream>>>(ei, btot, resv, pack);
    bucket_place_kernel<<<NBKT, 256, 0, stream>>>(btot, pack, off, sorted2);
    agg_kernel         <<<2048, 256, 0, stream>>>(x, ea, off, sorted2, pre, aggEA);
    mlp1g_kernel       <<<N_BLK, 256, 0, stream>>>(pre, aggEA, off, W1, wcbuf,
                                                   becbuf, b1, h, sums, sumsq);
    mlp2g_kernel       <<<N_BLK, 256, 0, stream>>>(h, W2, b2, sums, sumsq,
                                                   gamma, beta, (float*)d_out);
}

// Round 9
// 306.723 us; speedup vs baseline: 1.3730x; 1.0206x over previous
//
#include <hip/hip_runtime.h>

#define N_NODES 50000
#define N_EDGES 800000
#define D 64          // D_IN == D_OUT
#define ED 32         // EDGE_DIM
#define BN_EPS 1e-5f

#define NBKT 250      // buckets
#define NPB  200      // nodes per bucket (250*200 = 50000)
#define NB_HIST 500   // blocks for bin passes
#define EPB  1600     // edges per bin block (500*1600 = 800000)

// ---- workspace layout (32-bit word indices) -------------------------------
#define WS_SUMS     0
#define WS_SUMSQ    64
#define WS_BTOT     128                       // 256 ints (250 used)
#define WS_RESV     384                       // 256 ints (250 used)
#define WS_ZERO_END 640                       // memset [0, here) = 2.5 KB
#define WS_OFF      640                       // 50004 ints
#define WS_PACK     50644                     // uint2 x 800k (byte 202576, 8B ok)
#define WS_SRC2     (WS_PACK + 2 * N_EDGES)   // 1650644 (byte 6602576, 8B ok)
#define WS_AGGEA    (WS_SRC2 + 2 * N_EDGES)   // 3250644 (byte 13002576, 16B ok)
#define WS_PRE      (WS_AGGEA + N_NODES * ED) // 4850644 (byte 19402576, 16B ok)
#define WS_H        (WS_PRE + N_NODES * D)    // 8050644 (byte 32202576, 16B ok)
#define WS_WC       (WS_H + N_NODES * D)      // 11250644 (byte 45002576, 16B ok)
#define WS_BEC      (WS_WC + ED * D)          // 11252692
// total ~ 45 MB (ws proved >= 68 MB)

#define N_BLK ((N_NODES + 63) / 64)   // 782 GEMM tiles

// ---------------------------------------------------------------------------
// Fold edge MLP into main GEMM: wc = We@W1 [32x64], bec = be@W1 [64]
__global__ __launch_bounds__(256) void foldw_kernel(
    const float* __restrict__ We, const float* __restrict__ W1,
    const float* __restrict__ be, float* __restrict__ wc, float* __restrict__ bec)
{
    const int idx = blockIdx.x * 256 + threadIdx.x;
    if (idx < ED * D) {
        const int j = idx >> 6, f = idx & 63;
        float a = 0.f;
        for (int k = 0; k < D; ++k) a += We[j * D + k] * W1[k * D + f];
        wc[idx] = a;
    }
    if (idx < D) {
        float a = 0.f;
        for (int k = 0; k < D; ++k) a += be[k] * W1[k * D + idx];
        bec[idx] = a;
    }
}

// ---------------------------------------------------------------------------
// Pass 1: per-block LDS histogram of dst buckets -> global bucket totals
__global__ __launch_bounds__(256) void bin_hist_kernel(
    const int* __restrict__ dst, int* __restrict__ btot)
{
    __shared__ int hist[NBKT];
    const int t = threadIdx.x;
    if (t < NBKT) hist[t] = 0;
    __syncthreads();
    const int e0 = blockIdx.x * EPB;
    for (int i = t; i < EPB; i += 256)
        atomicAdd(&hist[dst[e0 + i] / NPB], 1);
    __syncthreads();
    if (t < NBKT) atomicAdd(&btot[t], hist[t]);
}

// ---------------------------------------------------------------------------
// Pass 2: bucket-grouped scatter with per-(block,bucket) contiguous segments.
// Each block: in-block scan of btot -> bucket bases; LDS hist of its chunk;
// ONE global atomic per bucket reserves a contiguous segment; packed writes
// land in short contiguous runs (low 64B-line amplification).
__global__ __launch_bounds__(256) void bin_scatter_kernel(
    const int* __restrict__ ei, const int* __restrict__ btot,
    int* __restrict__ resv, uint2* __restrict__ pack)
{
    __shared__ int sA[256], sB[256];
    __shared__ int bb[NBKT];                  // exclusive bucket bases
    __shared__ int hist[NBKT], seg[NBKT], lcur[NBKT];
    const int t = threadIdx.x;
    if (t < NBKT) { hist[t] = 0; lcur[t] = 0; }
    sA[t] = (t < NBKT) ? btot[t] : 0;
    __syncthreads();
    int* cur = sA; int* nxt = sB;
    for (int o = 1; o < 256; o <<= 1) {       // inclusive scan of 256
        nxt[t] = cur[t] + (t >= o ? cur[t - o] : 0);
        __syncthreads();
        int* tmp = cur; cur = nxt; nxt = tmp;
    }
    if (t < NBKT) bb[t] = (t == 0) ? 0 : cur[t - 1];
    __syncthreads();

    const int e0 = blockIdx.x * EPB;
    for (int i = t; i < EPB; i += 256)        // phase A: chunk histogram
        atomicAdd(&hist[ei[N_EDGES + e0 + i] / NPB], 1);
    __syncthreads();
    if (t < NBKT) seg[t] = bb[t] + atomicAdd(&resv[t], hist[t]);
    __syncthreads();
    for (int i = t; i < EPB; i += 256) {      // phase C: place into segment
        const int e = e0 + i;
        const int s = ei[e];
        const int d = ei[N_EDGES + e];
        const int bkt = d / NPB;
        const int r = atomicAdd(&lcur[bkt], 1);
        pack[seg[bkt] + r] = make_uint2(((unsigned)d << 16) | (unsigned)s,
                                        (unsigned)e);
    }
}

// ---------------------------------------------------------------------------
// Pass 3: one block per bucket (512 thr). LDS per-node histogram + scan ->
// off[] (replaces count/scan kernels); then final placement. All writes land
// in a ~25KB contiguous region per block -> L2 assembles full lines.
__global__ __launch_bounds__(512) void bucket_place_kernel(
    const int* __restrict__ btot, const uint2* __restrict__ pack,
    int* __restrict__ off, int2* __restrict__ sorted)
{
    __shared__ int sA[256], sB[256];
    __shared__ int cnt[NPB], lcur[NPB];
    __shared__ int pA[256], pB[256];
    __shared__ int sBase, sNE;
    const int t = threadIdx.x;
    const int j = blockIdx.x;
    if (t < 256) sA[t] = (t < NBKT) ? btot[t] : 0;
    if (t < NPB) { cnt[t] = 0; lcur[t] = 0; }
    __syncthreads();
    int* cur = sA; int* nxt = sB;
    for (int o = 1; o < 256; o <<= 1) {       // bucket bases (inclusive scan)
        if (t < 256) nxt[t] = cur[t] + (t >= o ? cur[t - o] : 0);
        __syncthreads();
        int* tmp = cur; cur = nxt; nxt = tmp;
    }
    if (t == 0) { sBase = (j == 0) ? 0 : cur[j - 1]; sNE = btot[j]; }
    __syncthreads();
    const int base = sBase, nE = sNE;
    const uint2* pp = pack + base;

    for (int i = t; i < nE; i += 512)         // per-node histogram
        atomicAdd(&cnt[(int)(pp[i].x >> 16) - j * NPB], 1);
    __syncthreads();
    if (t < 256) pA[t] = (t < NPB) ? cnt[t] : 0;
    __syncthreads();
    int* c2 = pA; int* n2 = pB;
    for (int o = 1; o < 256; o <<= 1) {       // per-node inclusive scan
        if (t < 256) n2[t] = c2[t] + (t >= o ? c2[t - o] : 0);
        __syncthreads();
        int* tmp = c2; c2 = n2; n2 = tmp;
    }
    if (t < NPB) {                            // n2 := exclusive starts; off[]
        const int excl = (t == 0) ? 0 : c2[t - 1];
        n2[t] = excl;
        off[j * NPB + t] = base + excl;
    }
    if (j == NBKT - 1 && t == 0) off[N_NODES] = N_EDGES;
    __syncthreads();
    for (int i = t; i < nE; i += 512) {       // final placement
        const uint2 w = pp[i];
        const int dl = (int)(w.x >> 16) - j * NPB;
        const int r = atomicAdd(&lcur[dl], 1);
        sorted[base + n2[dl] + r] = make_int2((int)w.y, (int)(w.x & 0xffffu));
    }
}

// ---------------------------------------------------------------------------
// Pure gather, no LDS -> full occupancy. Per node (wave):
//   pre[node]   = x[node] + sum_e x[src[e]]        (256B rows, lanes 0..63)
//   aggEA[node] = sum_e ea[eid[e]]                 (128B rows, 2 edges/instr)
__global__ __launch_bounds__(256) void agg_kernel(
    const float* __restrict__ x, const float* __restrict__ ea,
    const int* __restrict__ off, const int2* __restrict__ sorted,
    float* __restrict__ pre, float* __restrict__ aggEA)
{
    const int f = threadIdx.x & 63;
    const int w = threadIdx.x >> 6;
    const int fe = f & 31;
    const bool lo = (f < 32);
    const int nwv = gridDim.x * 4;
    for (int node = blockIdx.x * 4 + w; node < N_NODES; node += nwv) {
        const int start = __builtin_amdgcn_readfirstlane(off[node]);
        const int n     = __builtin_amdgcn_readfirstlane(off[node + 1]) - start;
        const int2* sp = sorted + start;
        float s = x[(size_t)node * D + f];
        float ax = 0.f, ay = 0.f;
        int it = 0;
        if (n >= 8) {
            int2 c0 = sp[0], c1 = sp[1], c2 = sp[2], c3 = sp[3];
            int2 c4 = sp[4], c5 = sp[5], c6 = sp[6], c7 = sp[7];
            for (; it + 16 <= n; it += 8) {
                const int2 n0 = sp[it + 8],  n1 = sp[it + 9];
                const int2 n2 = sp[it + 10], n3 = sp[it + 11];
                const int2 n4 = sp[it + 12], n5 = sp[it + 13];
                const int2 n6 = sp[it + 14], n7 = sp[it + 15];
                s += x[(size_t)c0.y * D + f]; s += x[(size_t)c1.y * D + f];
                s += x[(size_t)c2.y * D + f]; s += x[(size_t)c3.y * D + f];
                s += x[(size_t)c4.y * D + f]; s += x[(size_t)c5.y * D + f];
                s += x[(size_t)c6.y * D + f]; s += x[(size_t)c7.y * D + f];
                ax += ea[(size_t)(lo ? c0.x : c1.x) * ED + fe];
                ax += ea[(size_t)(lo ? c2.x : c3.x) * ED + fe];
                ay += ea[(size_t)(lo ? c4.x : c5.x) * ED + fe];
                ay += ea[(size_t)(lo ? c6.x : c7.x) * ED + fe];
                c0 = n0; c1 = n1; c2 = n2; c3 = n3;
                c4 = n4; c5 = n5; c6 = n6; c7 = n7;
            }
            s += x[(size_t)c0.y * D + f]; s += x[(size_t)c1.y * D + f];
            s += x[(size_t)c2.y * D + f]; s += x[(size_t)c3.y * D + f];
            s += x[(size_t)c4.y * D + f]; s += x[(size_t)c5.y * D + f];
            s += x[(size_t)c6.y * D + f]; s += x[(size_t)c7.y * D + f];
            ax += ea[(size_t)(lo ? c0.x : c1.x) * ED + fe];
            ax += ea[(size_t)(lo ? c2.x : c3.x) * ED + fe];
            ay += ea[(size_t)(lo ? c4.x : c5.x) * ED + fe];
            ay += ea[(size_t)(lo ? c6.x : c7.x) * ED + fe];
            it += 8;
        }
        for (; it < n; ++it) {               // tail: 0..7 edges
            const int2 p = sp[it];
            s += x[(size_t)p.y * D + f];
            if (lo) ax += ea[(size_t)p.x * ED + fe];
        }
        pre[(size_t)node * D + f] = s;
        ax += ay;
        ax += __shfl_xor(ax, 32);            // even-edge + odd-edge halves
        if (lo) aggEA[(size_t)node * ED + fe] = ax;
    }
}

// ---------------------------------------------------------------------------
// MLP1 as tiled GEMM: h[64n x 64f] = [pre|aggEA] @ [W1;Wc] + deg*bec + b1.
// Every dynamic index targets LDS (spill-proof). BN stats fused in epilogue.
__global__ __launch_bounds__(256) void mlp1g_kernel(
    const float* __restrict__ pre, const float* __restrict__ aggEA,
    const int* __restrict__ off,
    const float* __restrict__ W1, const float* __restrict__ wc,
    const float* __restrict__ bec, const float* __restrict__ b1,
    float* __restrict__ h, float* __restrict__ sums, float* __restrict__ sumsq)
{
    __shared__ float As[64 * 100];   // [node][k] k:0-63 pre, 64-95 aggEA
    __shared__ float Bs[96 * 64];    // [k][f]
    __shared__ float4 sb1v[16];
    __shared__ float4 sbecv[16];
    __shared__ float sDeg[64];
    const int tid = threadIdx.x;
    const int base = blockIdx.x * 64;

    for (int i = tid; i < 64 * 16; i += 256)
        ((float4*)Bs)[i] = ((const float4*)W1)[i];
    for (int i = tid; i < 32 * 16; i += 256)
        ((float4*)Bs)[64 * 16 + i] = ((const float4*)wc)[i];
    if (tid < 16)      sb1v[tid] = ((const float4*)b1)[tid];
    else if (tid < 32) sbecv[tid - 16] = ((const float4*)bec)[tid - 16];
    if (tid < 64) {
        const int node = base + tid;
        sDeg[tid] = (node < N_NODES) ? (float)(off[node + 1] - off[node]) : 0.f;
    }
    #pragma unroll
    for (int r = 0; r < 4; ++r) {
        const int idx = tid + 256 * r;
        const int nl = idx >> 4, c4 = idx & 15;
        const bool v = (base + nl) < N_NODES;
        const float4 t = v ? ((const float4*)pre)[(size_t)(base + nl) * 16 + c4]
                           : make_float4(0.f, 0.f, 0.f, 0.f);
        *(float4*)&As[nl * 100 + c4 * 4] = t;
    }
    #pragma unroll
    for (int r = 0; r < 2; ++r) {
        const int idx = tid + 256 * r;
        const int nl = idx >> 3, c4 = idx & 7;
        const bool v = (base + nl) < N_NODES;
        const float4 t = v ? ((const float4*)aggEA)[(size_t)(base + nl) * 8 + c4]
                           : make_float4(0.f, 0.f, 0.f, 0.f);
        *(float4*)&As[nl * 100 + 64 + c4 * 4] = t;
    }
    __syncthreads();

    const int tx = tid & 15, ty = tid >> 4;
    const int r0 = ty * 4;
    const float4 bb = sb1v[tx];
    const float4 bc = sbecv[tx];
    float4 acc0, acc1, acc2, acc3;
    acc0.x = bb.x + sDeg[r0+0]*bc.x; acc0.y = bb.y + sDeg[r0+0]*bc.y;
    acc0.z = bb.z + sDeg[r0+0]*bc.z; acc0.w = bb.w + sDeg[r0+0]*bc.w;
    acc1.x = bb.x + sDeg[r0+1]*bc.x; acc1.y = bb.y + sDeg[r0+1]*bc.y;
    acc1.z = bb.z + sDeg[r0+1]*bc.z; acc1.w = bb.w + sDeg[r0+1]*bc.w;
    acc2.x = bb.x + sDeg[r0+2]*bc.x; acc2.y = bb.y + sDeg[r0+2]*bc.y;
    acc2.z = bb.z + sDeg[r0+2]*bc.z; acc2.w = bb.w + sDeg[r0+2]*bc.w;
    acc3.x = bb.x + sDeg[r0+3]*bc.x; acc3.y = bb.y + sDeg[r0+3]*bc.y;
    acc3.z = bb.z + sDeg[r0+3]*bc.z; acc3.w = bb.w + sDeg[r0+3]*bc.w;

    for (int k4 = 0; k4 < 24; ++k4) {
        const int k = k4 * 4;
        const float4 a0 = *(const float4*)&As[(r0+0)*100 + k];
        const float4 a1 = *(const float4*)&As[(r0+1)*100 + k];
        const float4 a2 = *(const float4*)&As[(r0+2)*100 + k];
        const float4 a3 = *(const float4*)&As[(r0+3)*100 + k];
        const float4 w0 = *(const float4*)&Bs[(k+0)*64 + tx*4];
        const float4 w1v = *(const float4*)&Bs[(k+1)*64 + tx*4];
        const float4 w2v = *(const float4*)&Bs[(k+2)*64 + tx*4];
        const float4 w3v = *(const float4*)&Bs[(k+3)*64 + tx*4];
        acc0.x += a0.x*w0.x + a0.y*w1v.x + a0.z*w2v.x + a0.w*w3v.x;
        acc0.y += a0.x*w0.y + a0.y*w1v.y + a0.z*w2v.y + a0.w*w3v.y;
        acc0.z += a0.x*w0.z + a0.y*w1v.z + a0.z*w2v.z + a0.w*w3v.z;
        acc0.w += a0.x*w0.w + a0.y*w1v.w + a0.z*w2v.w + a0.w*w3v.w;
        acc1.x += a1.x*w0.x + a1.y*w1v.x + a1.z*w2v.x + a1.w*w3v.x;
        acc1.y += a1.x*w0.y + a1.y*w1v.y + a1.z*w2v.y + a1.w*w3v.y;
        acc1.z += a1.x*w0.z + a1.y*w1v.z + a1.z*w2v.z + a1.w*w3v.z;
        acc1.w += a1.x*w0.w + a1.y*w1v.w + a1.z*w2v.w + a1.w*w3v.w;
        acc2.x += a2.x*w0.x + a2.y*w1v.x + a2.z*w2v.x + a2.w*w3v.x;
        acc2.y += a2.x*w0.y + a2.y*w1v.y + a2.z*w2v.y + a2.w*w3v.y;
        acc2.z += a2.x*w0.z + a2.y*w1v.z + a2.z*w2v.z + a2.w*w3v.z;
        acc2.w += a2.x*w0.w + a2.y*w1v.w + a2.z*w2v.w + a2.w*w3v.w;
        acc3.x += a3.x*w0.x + a3.y*w1v.x + a3.z*w2v.x + a3.w*w3v.x;
        acc3.y += a3.x*w0.y + a3.y*w1v.y + a3.z*w2v.y + a3.w*w3v.y;
        acc3.z += a3.x*w0.z + a3.y*w1v.z + a3.z*w2v.z + a3.w*w3v.z;
        acc3.w += a3.x*w0.w + a3.y*w1v.w + a3.z*w2v.w + a3.w*w3v.w;
    }

    float4 ps = make_float4(0.f, 0.f, 0.f, 0.f);
    float4 pq = make_float4(0.f, 0.f, 0.f, 0.f);
    {
        const int n0 = base + r0;
        if (n0 + 0 < N_NODES) {
            ((float4*)h)[(size_t)(n0+0)*16 + tx] = acc0;
            ps.x += acc0.x; ps.y += acc0.y; ps.z += acc0.z; ps.w += acc0.w;
            pq.x += acc0.x*acc0.x; pq.y += acc0.y*acc0.y;
            pq.z += acc0.z*acc0.z; pq.w += acc0.w*acc0.w;
        }
        if (n0 + 1 < N_NODES) {
            ((float4*)h)[(size_t)(n0+1)*16 + tx] = acc1;
            ps.x += acc1.x; ps.y += acc1.y; ps.z += acc1.z; ps.w += acc1.w;
            pq.x += acc1.x*acc1.x; pq.y += acc1.y*acc1.y;
            pq.z += acc1.z*acc1.z; pq.w += acc1.w*acc1.w;
        }
        if (n0 + 2 < N_NODES) {
            ((float4*)h)[(size_t)(n0+2)*16 + tx] = acc2;
            ps.x += acc2.x; ps.y += acc2.y; ps.z += acc2.z; ps.w += acc2.w;
            pq.x += acc2.x*acc2.x; pq.y += acc2.y*acc2.y;
            pq.z += acc2.z*acc2.z; pq.w += acc2.w*acc2.w;
        }
        if (n0 + 3 < N_NODES) {
            ((float4*)h)[(size_t)(n0+3)*16 + tx] = acc3;
            ps.x += acc3.x; ps.y += acc3.y; ps.z += acc3.z; ps.w += acc3.w;
            pq.x += acc3.x*acc3.x; pq.y += acc3.y*acc3.y;
            pq.z += acc3.z*acc3.z; pq.w += acc3.w*acc3.w;
        }
    }
    __syncthreads();
    float* sS = Bs;                 // reuse B-tile LDS for BN reduction
    float* sQ = Bs + 1024;
    sS[ty*64 + tx*4 + 0] = ps.x; sS[ty*64 + tx*4 + 1] = ps.y;
    sS[ty*64 + tx*4 + 2] = ps.z; sS[ty*64 + tx*4 + 3] = ps.w;
    sQ[ty*64 + tx*4 + 0] = pq.x; sQ[ty*64 + tx*4 + 1] = pq.y;
    sQ[ty*64 + tx*4 + 2] = pq.z; sQ[ty*64 + tx*4 + 3] = pq.w;
    __syncthreads();
    if (tid < 64) {
        float s = 0.f, q = 0.f;
        #pragma unroll
        for (int r = 0; r < 16; ++r) { s += sS[r*64 + tid]; q += sQ[r*64 + tid]; }
        unsafeAtomicAdd(&sums[tid], s);
        unsafeAtomicAdd(&sumsq[tid], q);
    }
}

// ---------------------------------------------------------------------------
// MLP2 as tiled GEMM: out = relu(h*sc+sh) @ W2 + b2 (BN applied at A-staging)
__global__ __launch_bounds__(256) void mlp2g_kernel(
    const float* __restrict__ h, const float* __restrict__ W2,
    const float* __restrict__ b2, const float* __restrict__ sums,
    const float* __restrict__ sumsq, const float* __restrict__ gamma,
    const float* __restrict__ beta, float* __restrict__ out)
{
    __shared__ float As[64 * 68];
    __shared__ float Bs[64 * 64];
    __shared__ float4 sb2v[16];
    __shared__ float4 sscv[16];
    __shared__ float4 sshv[16];
    const int tid = threadIdx.x;
    const int base = blockIdx.x * 64;

    for (int i = tid; i < 64 * 16; i += 256)
        ((float4*)Bs)[i] = ((const float4*)W2)[i];
    if (tid < 16) sb2v[tid] = ((const float4*)b2)[tid];
    if (tid < 64) {
        const float inv_n = 1.0f / (float)N_NODES;
        const float mean = sums[tid] * inv_n;
        const float var  = sumsq[tid] * inv_n - mean * mean;   // biased, like jnp.var
        const float sc   = gamma[tid] * rsqrtf(var + BN_EPS);
        ((float*)sscv)[tid] = sc;
        ((float*)sshv)[tid] = beta[tid] - mean * sc;
    }
    __syncthreads();

    #pragma unroll
    for (int r = 0; r < 4; ++r) {
        const int idx = tid + 256 * r;
        const int nl = idx >> 4, c4 = idx & 15;
        const bool v = (base + nl) < N_NODES;
        const float4 t = v ? ((const float4*)h)[(size_t)(base + nl) * 16 + c4]
                           : make_float4(0.f, 0.f, 0.f, 0.f);
        const float4 c = sscv[c4];
        const float4 s = sshv[c4];
        float4 rv;
        rv.x = fmaxf(t.x * c.x + s.x, 0.f);
        rv.y = fmaxf(t.y * c.y + s.y, 0.f);
        rv.z = fmaxf(t.z * c.z + s.z, 0.f);
        rv.w = fmaxf(t.w * c.w + s.w, 0.f);
        *(float4*)&As[nl * 68 + c4 * 4] = rv;
    }
    __syncthreads();

    const int tx = tid & 15, ty = tid >> 4;
    const int r0 = ty * 4;
    const float4 bb = sb2v[tx];
    float4 acc0 = bb, acc1 = bb, acc2 = bb, acc3 = bb;

    for (int k4 = 0; k4 < 16; ++k4) {
        const int k = k4 * 4;
        const float4 a0 = *(const float4*)&As[(r0+0)*68 + k];
        const float4 a1 = *(const float4*)&As[(r0+1)*68 + k];
        const float4 a2 = *(const float4*)&As[(r0+2)*68 + k];
        const float4 a3 = *(const float4*)&As[(r0+3)*68 + k];
        const float4 w0 = *(const float4*)&Bs[(k+0)*64 + tx*4];
        const float4 w1v = *(const float4*)&Bs[(k+1)*64 + tx*4];
        const float4 w2v = *(const float4*)&Bs[(k+2)*64 + tx*4];
        const float4 w3v = *(const float4*)&Bs[(k+3)*64 + tx*4];
        acc0.x += a0.x*w0.x + a0.y*w1v.x + a0.z*w2v.x + a0.w*w3v.x;
        acc0.y += a0.x*w0.y + a0.y*w1v.y + a0.z*w2v.y + a0.w*w3v.y;
        acc0.z += a0.x*w0.z + a0.y*w1v.z + a0.z*w2v.z + a0.w*w3v.z;
        acc0.w += a0.x*w0.w + a0.y*w1v.w + a0.z*w2v.w + a0.w*w3v.w;
        acc1.x += a1.x*w0.x + a1.y*w1v.x + a1.z*w2v.x + a1.w*w3v.x;
        acc1.y += a1.x*w0.y + a1.y*w1v.y + a1.z*w2v.y + a1.w*w3v.y;
        acc1.z += a1.x*w0.z + a1.y*w1v.z + a1.z*w2v.z + a1.w*w3v.z;
        acc1.w += a1.x*w0.w + a1.y*w1v.w + a1.z*w2v.w + a1.w*w3v.w;
        acc2.x += a2.x*w0.x + a2.y*w1v.x + a2.z*w2v.x + a2.w*w3v.x;
        acc2.y += a2.x*w0.y + a2.y*w1v.y + a2.z*w2v.y + a2.w*w3v.y;
        acc2.z += a2.x*w0.z + a2.y*w1v.z + a2.z*w2v.z + a2.w*w3v.z;
        acc2.w += a2.x*w0.w + a2.y*w1v.w + a2.z*w2v.w + a2.w*w3v.w;
        acc3.x += a3.x*w0.x + a3.y*w1v.x + a3.z*w2v.x + a3.w*w3v.x;
        acc3.y += a3.x*w0.y + a3.y*w1v.y + a3.z*w2v.y + a3.w*w3v.y;
        acc3.z += a3.x*w0.z + a3.y*w1v.z + a3.z*w2v.z + a3.w*w3v.z;
        acc3.w += a3.x*w0.w + a3.y*w1v.w + a3.z*w2v.w + a3.w*w3v.w;
    }

    const int n0 = base + r0;
    if (n0 + 0 < N_NODES) ((float4*)out)[(size_t)(n0+0)*16 + tx] = acc0;
    if (n0 + 1 < N_NODES) ((float4*)out)[(size_t)(n0+1)*16 + tx] = acc1;
    if (n0 + 2 < N_NODES) ((float4*)out)[(size_t)(n0+2)*16 + tx] = acc2;
    if (n0 + 3 < N_NODES) ((float4*)out)[(size_t)(n0+3)*16 + tx] = acc3;
}

// ---------------------------------------------------------------------------
extern "C" void kernel_launch(void* const* d_in, const int* in_sizes, int n_in,
                              void* d_out, int out_size, void* d_ws, size_t ws_size,
                              hipStream_t stream) {
    const float* x     = (const float*)d_in[0];
    const int*   ei    = (const int*)  d_in[1];   // [2, E] int32
    const float* ea    = (const float*)d_in[2];
    const float* We    = (const float*)d_in[3];
    const float* be    = (const float*)d_in[4];
    const float* W1    = (const float*)d_in[5];
    const float* b1    = (const float*)d_in[6];
    const float* gamma = (const float*)d_in[7];
    const float* beta  = (const float*)d_in[8];
    const float* W2    = (const float*)d_in[9];
    const float* b2    = (const float*)d_in[10];

    float* ws      = (float*)d_ws;
    float* sums    = ws + WS_SUMS;
    float* sumsq   = ws + WS_SUMSQ;
    int*   btot    = (int*)(ws + WS_BTOT);
    int*   resv    = (int*)(ws + WS_RESV);
    int*   off     = (int*)(ws + WS_OFF);
    uint2* pack    = (uint2*)(ws + WS_PACK);
    int2*  sorted2 = (int2*)(ws + WS_SRC2);
    float* aggEA   = ws + WS_AGGEA;
    float* pre     = ws + WS_PRE;
    float* h       = ws + WS_H;
    float* wcbuf   = ws + WS_WC;
    float* becbuf  = ws + WS_BEC;

    hipMemsetAsync(ws, 0, (size_t)WS_ZERO_END * sizeof(float), stream);

    foldw_kernel       <<<8, 256, 0, stream>>>(We, W1, be, wcbuf, becbuf);
    bin_hist_kernel    <<<NB_HIST, 256, 0, stream>>>(ei + N_EDGES, btot);
    bin_scatter_kernel <<<NB_HIST, 256, 0, stream>>>(ei, btot, resv, pack);
    bucket_place_kernel<<<NBKT, 512, 0, stream>>>(btot, pack, off, sorted2);
    agg_kernel         <<<2048, 256, 0, stream>>>(x, ea, off, sorted2, pre, aggEA);
    mlp1g_kernel       <<<N_BLK, 256, 0, stream>>>(pre, aggEA, off, W1, wcbuf,
                                                   becbuf, b1, h, sums, sumsq);
    mlp2g_kernel       <<<N_BLK, 256, 0, stream>>>(h, W2, b2, sums, sumsq,
                                                   gamma, beta, (float*)d_out);
}